// Round 5
// baseline (553.746 us; speedup 1.0000x reference)
//
#include <hip/hip_runtime.h>
#include <math.h>

#define DIMX 480

typedef float v4f __attribute__((ext_vector_type(4)));
typedef _Float16 v8h __attribute__((ext_vector_type(8)));
typedef _Float16 v4h __attribute__((ext_vector_type(4)));

// ---------------------------------------------------------------------------
// CG tables, computed on HOST exactly per the reference (verified r1-r6; host
// port of the former device cg_init kernel, removed to save a serial launch).
//  0:(0,0,0) 0   1:(0,1,1) 1    2:(0,2,2) 10   3:(1,0,1) 35   4:(1,1,0) 44
//  5:(1,1,2) 53  6:(1,2,1) 98   7:(2,0,2) 143  8:(2,1,1) 168  9:(2,2,0) 213
// 10:(2,2,2) 238  total 363
// ---------------------------------------------------------------------------
// LPT dispatch order over 12 units (longest first) + same-path grouping for
// L2 locality. Unit 11 = second K-half of path 0 (writes pc cols 0..128).
__constant__ int c_order[12] = {8,5,10,3,4,7,9,0,11,6,1,2};

struct hcplx { double re, im; };
static inline hcplx hcmul(hcplx a, hcplx b) {
    return { a.re*b.re - a.im*b.im, a.re*b.im + a.im*b.re };
}
static double hdfact(int n) { double r = 1.0; for (int i = 2; i <= n; ++i) r *= (double)i; return r; }

static double hsu2cg(int j1, int j2, int j3, int m1, int m2) {
    int m3 = m1 + m2;
    if (m3 < -j3 || m3 > j3) return 0.0;
    double pref = (2.0*j3 + 1.0)
        * hdfact(j3 + j1 - j2) * hdfact(j3 - j1 + j2) * hdfact(j1 + j2 - j3)
        / hdfact(j1 + j2 + j3 + 1)
        * hdfact(j3 + m3) * hdfact(j3 - m3) * hdfact(j1 - m1) * hdfact(j1 + m1)
        * hdfact(j2 - m2) * hdfact(j2 + m2);
    pref = sqrt(pref);
    double s = 0.0;
    for (int k = 0; k <= j1 + j2 - j3; ++k) {
        if (j1 - m1 - k < 0 || j2 + m2 - k < 0 ||
            j3 - j2 + m1 + k < 0 || j3 - j1 - m2 + k < 0) continue;
        double d = hdfact(k) * hdfact(j1 + j2 - j3 - k) * hdfact(j1 - m1 - k)
                 * hdfact(j2 + m2 - k) * hdfact(j3 - j2 + m1 + k) * hdfact(j3 - j1 - m2 + k);
        s += ((k & 1) ? -1.0 : 1.0) / d;
    }
    return pref * s;
}

static hcplx hQval(int l, int mi, int ri) {
    const double is2 = 0.70710678118654752440;
    int m = mi - l;
    hcplx q = {0.0, 0.0};
    if (m < 0) {
        if (ri == l - m)       q = { is2, 0.0 };
        else if (ri == l + m)  q = { 0.0, -is2 };
    } else if (m == 0) {
        if (ri == l)           q = { 1.0, 0.0 };
    } else {
        double s = (m & 1) ? -1.0 : 1.0;
        if (ri == l + m)       q = { s * is2, 0.0 };
        else if (ri == l - m)  q = { 0.0, s * is2 };
    }
    int ph = l & 3;
    hcplx r;
    if (ph == 0)      r = q;
    else if (ph == 1) r = {  q.im, -q.re };
    else if (ph == 2) r = { -q.re, -q.im };
    else              r = { -q.im,  q.re };
    return r;
}

static void build_cg_host(float* cgout) {
    static const int pl[11][3] = {
        {0,0,0},{0,1,1},{0,2,2},{1,0,1},{1,1,0},{1,1,2},
        {1,2,1},{2,0,2},{2,1,1},{2,2,0},{2,2,2}};
    static const int cgo[11] = {0,1,10,35,44,53,98,143,168,213,238};
    for (int p = 0; p < 11; ++p) {
        int l1 = pl[p][0], l2 = pl[p][1], l3 = pl[p][2];
        int D2 = 2*l2 + 1, D3 = 2*l3 + 1;
        int D = (2*l1 + 1) * D2 * D3;
        double vals[125];
        double ss = 0.0;
        for (int e = 0; e < D; ++e) {
            int j  = e / (D2 * D3);
            int l_ = (e / D3) % D2;
            int n  = e % D3;
            double val = 0.0;
            for (int m1 = -l1; m1 <= l1; ++m1)
                for (int m2 = -l2; m2 <= l2; ++m2) {
                    int m3 = m1 + m2;
                    if (m3 < -l3 || m3 > l3) continue;
                    double cgv = hsu2cg(l1, l2, l3, m1, m2);
                    if (cgv == 0.0) continue;
                    hcplx t = hcmul(hcmul(hQval(l1, l1 + m1, j), hQval(l2, l2 + m2, l_)),
                                    hQval(l3, l3 + m3, n));
                    val += t.re * cgv;
                }
            vals[e] = val; ss += val * val;
        }
        double nrm = sqrt(ss);
        for (int e = 0; e < D; ++e) cgout[cgo[p] + e] = (float)(vals[e] / nrm);
    }
}

// ---------------------------------------------------------------------------
// Wt swizzle: wt2 holds fp16 B-fragments in wave-coalesced order (r6 layout).
// chunk cc = (kblk*(N/16) + nblk)*64 + quad*16 + l ; elem j ->
// Wt[n = nblk*16+l][k = kblk*32 + quad*8 + j].
// sec offs (elems): 0 / 2752512 / 4063232 ; total 4489216.
// ---------------------------------------------------------------------------
__global__ __launch_bounds__(256) void wt2_kernel(const float* __restrict__ w,
                                                  _Float16* __restrict__ wt2) {
    int c = blockIdx.x * 256 + threadIdx.x;
    int sec, cc;
    if (c < 344064)      { sec = 0; cc = c; }
    else if (c < 507904) { sec = 1; cc = c - 344064; }
    else                 { sec = 2; cc = c - 507904; }
    int l = cc & 15, quad = (cc >> 4) & 3;
    int nblk, kblk, N; size_t soff;
    if (sec == 0)      { nblk = (cc >> 6) & 7; kblk = cc >> 9; N = 128; soff = 0; }
    else if (sec == 1) { nblk = (cc >> 6) & 3; kblk = cc >> 8; N = 64;  soff = 2752512; }
    else               { nblk = (cc >> 6) & 1; kblk = cc >> 7; N = 32;  soff = 4063232; }
    int n = nblk * 16 + l;
    int k = kblk * 32 + quad * 8;
    int rb, pb;
    if (sec == 0) {
        if (k < 16384)      { rb = 0;     pb = 0; }
        else if (k < 20480) { rb = 16384; pb = 3276800; }
        else                { rb = 20480; pb = 4325376; }
    } else if (sec == 1) {
        if (k < 8192)       { rb = 0;     pb = 2097152; }
        else if (k < 16384) { rb = 8192;  pb = 2752512; }
        else if (k < 18432) { rb = 16384; pb = 3932160; }
        else                { rb = 18432; pb = 4194304; }
    } else {
        if (k < 4096)       { rb = 0;     pb = 2621440; }
        else if (k < 8192)  { rb = 4096;  pb = 3801088; }
        else if (k < 12288) { rb = 8192;  pb = 4063232; }
        else                { rb = 12288; pb = 4456448; }
    }
    const float* src = w + pb + (size_t)(k - rb) * N + n;
    v8h o;
    #pragma unroll
    for (int j = 0; j < 8; ++j) o[j] = (_Float16)src[(size_t)j * N];
    *(v8h*)(&wt2[soff + (size_t)cc * 8]) = o;
}

// ---------------------------------------------------------------------------
static __device__ __forceinline__ void stage_tile(const float* __restrict__ x,
        int b0, int c0, int n4, int S, _Float16* __restrict__ d, int tid) {
    const int cnt = 32 * n4;
    for (int c = tid; c < cnt; c += 256) {
        int row = c / n4, ch = c - row * n4;
        float4 v = *(const float4*)(x + (size_t)(b0 + row) * DIMX + c0 + ch * 4);
        v4h p;
        p[0] = (_Float16)v.x; p[1] = (_Float16)v.y; p[2] = (_Float16)v.z; p[3] = (_Float16)v.w;
        *(v4h*)(&d[row * S + ch * 4]) = p;
    }
}

// f16-domain element extract (stays 16-bit; compiler uses op_sel halves)
#define XH(A, i) (A[(i) >> 3][(i) & 7])
// f32 extract (fallback kernel only)
#define XE(A, i) ((float)A[(i) >> 3][(i) & 7])

// Cross-wave kh-pair accumulator merge through LDS (reuses xs; max 24576 B).
// Hand-inlined macro with STATIC acc indices only: acc must never be
// address-taken (r1 post-mortem: pointer-escape demoted acc to scratch ->
// VGPR 48, WRITE_SIZE 545MB, no speedup). After this, kh==0 waves hold sums.
#define PAIR_REDUCE(NA)                                                  \
    {                                                                    \
        v4f* red_ = (v4f*)xs;                                            \
        __syncthreads();                                                 \
        if (kh) {                                                        \
            _Pragma("unroll")                                            \
            for (int a_ = 0; a_ < (NA); ++a_)                            \
                red_[(rt * 64 + lane) * (NA) + a_] = acc[a_];            \
        }                                                                \
        __syncthreads();                                                 \
        if (!kh) {                                                       \
            _Pragma("unroll")                                            \
            for (int a_ = 0; a_ < (NA); ++a_)                            \
                acc[a_] += red_[(rt * 64 + lane) * (NA) + a_];           \
        }                                                                \
    }

// ---------------------------------------------------------------------------
// Path-specialized kernel: 3072 blocks = 12 units x 256 batch-tiles of 32.
// fp16 pipeline (r4): af-fragments built with native f16 VALU; MFMA
// f32_16x16x32_f16. r5: __launch_bounds__(256,6) -> 6 blocks/CU (LDS 25600B
// x6 = 153.6KB <= 160KB; VGPR 56 <= 85 cap) to lift the 50%-static occupancy
// cap (r4 measured 40.5% occ with no pipe saturated -> latency-bound).
// Waves = (rt = row half, kh = K half); kh merged via PAIR_REDUCE.
//   out: p0a,p4,p9   pa: p1,p3,p7   pb: p2,p5,p8   pc: p0b,p6,p10
// ---------------------------------------------------------------------------
__global__ __launch_bounds__(256, 6) void tp_path(
    const float* __restrict__ x1, const float* __restrict__ x2,
    const _Float16* __restrict__ wt2, const float* __restrict__ cg,
    float* __restrict__ out, float* __restrict__ pa,
    float* __restrict__ pb, float* __restrict__ pc)
{
    __shared__ __align__(16) _Float16 xs[12800];
    const int tid  = threadIdx.x;
    const int lane = tid & 63;
    const int wv   = tid >> 6;
    const int quad = lane >> 4;
    const int l16  = lane & 15;
    const int rt   = wv & 1;
    const int kh   = wv >> 1;
    const int path = c_order[blockIdx.x >> 8];
    const int b0   = (blockIdx.x & 255) * 32;
    const int qil  = (quad * 16 + l16) * 8;
    const int lrow = rt * 16 + l16;

    const float c0n = sqrtf(1.0f / 21504.0f);
    const float c1n = sqrtf(3.0f / 20480.0f);
    const float c2n = sqrtf(5.0f / 13312.0f);

    switch (path) {
    case 0: case 11: { // (0,0,0) sec0, K 16384 split into halves of 8192
        float* __restrict__ dst = (path == 0) ? out : pc;
        const int ub = ((path == 11) ? 64 : 0) + kh * 32;
        const int S = 136;
        stage_tile(x1, b0, 0, 32, S, xs, tid);
        stage_tile(x2, b0, 0, 32, S, xs + 32*S, tid);
        __syncthreads();
        const _Float16* X1L = xs + lrow * S;
        const _Float16* X2L = xs + 32*S + lrow * S;
        const _Float16 s0h = (_Float16)(cg[0] * c0n);
        v4f acc[8];
        #pragma unroll
        for (int c = 0; c < 8; ++c) acc[c] = (v4f)0.f;
        #pragma unroll 1
        for (int u = ub; u < ub + 32; ++u) {
            const _Float16 sh = s0h * X1L[u];
            #pragma unroll 2
            for (int q4 = 0; q4 < 4; ++q4) {
                v8h xv = *(const v8h*)(X2L + 32*q4 + quad * 8);
                v8h af = xv * sh;                     // 4x v_pk_mul_f16
                const _Float16* bp = wt2 + (size_t)((u*4 + q4) * 8) * 512 + qil;
                #pragma unroll
                for (int ct = 0; ct < 8; ++ct) {
                    v8h bf = *(const v8h*)(bp + ct * 512);
                    acc[ct] = __builtin_amdgcn_mfma_f32_16x16x32_f16(af, bf, acc[ct], 0, 0, 0);
                }
            }
        }
        PAIR_REDUCE(8)
        if (!kh) {
            #pragma unroll
            for (int i = 0; i < 4; ++i) {
                int r = b0 + rt*16 + quad*4 + i;
                #pragma unroll
                for (int ct = 0; ct < 8; ++ct)
                    dst[(size_t)r * DIMX + ct*16 + l16] = acc[ct][i];
            }
        }
        break; }
    case 1: { // (1,1,0) sec0 -> pa, K 4096
        const int S = 200;
        stage_tile(x1, b0, 128, 48, S, xs, tid);
        stage_tile(x2, b0, 128, 48, S, xs + 32*S, tid);
        __syncthreads();
        const _Float16* X1L = xs + lrow * S;
        const _Float16* X2L = xs + 32*S + lrow * S;
        const float d0 = cg[44]*c0n, d1 = cg[48]*c0n, d2 = cg[52]*c0n;
        v4f acc[8];
        #pragma unroll
        for (int c = 0; c < 8; ++c) acc[c] = (v4f)0.f;
        #pragma unroll 1
        for (int tu = kh*32; tu < kh*32 + 32; ++tu) {
            const int u3 = 3 * tu;
            const _Float16 m0 = (_Float16)(d0*(float)X1L[u3]);
            const _Float16 m1 = (_Float16)(d1*(float)X1L[u3+1]);
            const _Float16 m2 = (_Float16)(d2*(float)X1L[u3+2]);
            #pragma unroll 1
            for (int h = 0; h < 2; ++h) {
                const int col = 96*h + 24*quad;
                v8h a[3];
                a[0] = *(const v8h*)(X2L + col);
                a[1] = *(const v8h*)(X2L + col + 8);
                a[2] = *(const v8h*)(X2L + col + 16);
                v8h af;
                #pragma unroll
                for (int j = 0; j < 8; ++j)
                    af[j] = m0*XH(a,3*j) + m1*XH(a,3*j+1) + m2*XH(a,3*j+2); // f16 fma chain
                const _Float16* bp = wt2 + (size_t)((512 + tu*2 + h) * 8) * 512 + qil;
                #pragma unroll
                for (int ct = 0; ct < 8; ++ct) {
                    v8h bf = *(const v8h*)(bp + ct * 512);
                    acc[ct] = __builtin_amdgcn_mfma_f32_16x16x32_f16(af, bf, acc[ct], 0, 0, 0);
                }
            }
        }
        PAIR_REDUCE(8)
        if (!kh) {
            #pragma unroll
            for (int i = 0; i < 4; ++i) {
                int r = b0 + rt*16 + quad*4 + i;
                #pragma unroll
                for (int ct = 0; ct < 8; ++ct)
                    pa[(size_t)r * DIMX + ct*16 + l16] = acc[ct][i];
            }
        }
        break; }
    case 2: { // (2,2,0) sec0 -> pb, K 1024
        const int S = 168;
        stage_tile(x1, b0, 320, 40, S, xs, tid);
        stage_tile(x2, b0, 320, 40, S, xs + 32*S, tid);
        __syncthreads();
        const _Float16* X1L = xs + lrow * S;
        const _Float16* X2L = xs + 32*S + lrow * S;
        v4f acc[8];
        #pragma unroll
        for (int c = 0; c < 8; ++c) acc[c] = (v4f)0.f;
        v8h a[5];   // x2 fragment is t-invariant: hoist out of the loop
        #pragma unroll
        for (int q = 0; q < 5; ++q) a[q] = *(const v8h*)(X2L + 40*quad + 8*q);
        #pragma unroll 1
        for (int t = kh*16; t < kh*16 + 16; ++t) {
            const int u5 = 5 * t;
            _Float16 m[5];
            #pragma unroll
            for (int kk = 0; kk < 5; ++kk)
                m[kk] = (_Float16)(cg[213+6*kk]*c0n*(float)X1L[u5+kk]);
            v8h af;
            #pragma unroll
            for (int j = 0; j < 8; ++j) {
                _Float16 s = (_Float16)0.f;
                #pragma unroll
                for (int kk = 0; kk < 5; ++kk) s += m[kk] * XH(a, 5*j+kk);
                af[j] = s;
            }
            const _Float16* bp = wt2 + (size_t)((640+t) * 8) * 512 + qil;
            #pragma unroll
            for (int ct = 0; ct < 8; ++ct) {
                v8h bf = *(const v8h*)(bp + ct * 512);
                acc[ct] = __builtin_amdgcn_mfma_f32_16x16x32_f16(af, bf, acc[ct], 0, 0, 0);
            }
        }
        PAIR_REDUCE(8)
        if (!kh) {
            #pragma unroll
            for (int i = 0; i < 4; ++i) {
                int r = b0 + rt*16 + quad*4 + i;
                #pragma unroll
                for (int ct = 0; ct < 8; ++ct)
                    pb[(size_t)r * DIMX + ct*16 + l16] = acc[ct][i];
            }
        }
        break; }
    case 3: { // (0,1,1) sec1 -> pa, K 8192
        const int S1 = 136, S2 = 200;
        stage_tile(x1, b0, 0,   32, S1, xs, tid);
        stage_tile(x2, b0, 128, 48, S2, xs + 32*S1, tid);
        __syncthreads();
        const _Float16* X1L = xs + lrow * S1;
        const _Float16* X2L = xs + 32*S1 + lrow * S2;
        const float g0 = cg[1]*c1n, g1 = cg[5]*c1n, g2 = cg[9]*c1n;
        v4f acc[12];   // [p*4 + cti]
        #pragma unroll
        for (int c = 0; c < 12; ++c) acc[c] = (v4f)0.f;
        #pragma unroll 1
        for (int tu = kh*64; tu < kh*64 + 64; ++tu) {
            const float xu = (float)X1L[tu];
            const _Float16 e0 = (_Float16)(g0*xu);
            const _Float16 e1 = (_Float16)(g1*xu);
            const _Float16 e2 = (_Float16)(g2*xu);
            #pragma unroll 1
            for (int h = 0; h < 2; ++h) {
                const int t = tu*2 + h;
                const int col = 96*h + 24*quad;
                v8h a[3];
                a[0] = *(const v8h*)(X2L + col);
                a[1] = *(const v8h*)(X2L + col + 8);
                a[2] = *(const v8h*)(X2L + col + 16);
                v8h af[3];
                #pragma unroll
                for (int j = 0; j < 8; ++j) {
                    af[0][j] = e0 * XH(a, 3*j);     // 1x v_mul_f16 each
                    af[1][j] = e1 * XH(a, 3*j+1);
                    af[2][j] = e2 * XH(a, 3*j+2);
                }
                const _Float16* bp = wt2 + 2752512 + (size_t)(t*4) * 512 + qil;
                #pragma unroll
                for (int cti = 0; cti < 4; ++cti) {
                    v8h bf = *(const v8h*)(bp + cti * 512);
                    #pragma unroll
                    for (int p = 0; p < 3; ++p)
                        acc[p*4+cti] = __builtin_amdgcn_mfma_f32_16x16x32_f16(af[p], bf, acc[p*4+cti], 0, 0, 0);
                }
            }
        }
        PAIR_REDUCE(12)
        if (!kh) {
            #pragma unroll
            for (int i = 0; i < 4; ++i) {
                int r = b0 + rt*16 + quad*4 + i;
                #pragma unroll
                for (int p = 0; p < 3; ++p)
                    #pragma unroll
                    for (int cti = 0; cti < 4; ++cti)
                        pa[(size_t)r * DIMX + 128 + (cti*16 + l16)*3 + p] = acc[p*4+cti][i];
            }
        }
        break; }
    case 4: { // (1,0,1) sec1 -> out, K 8192
        const int S1 = 200, S2 = 136;
        stage_tile(x1, b0, 128, 48, S1, xs, tid);
        stage_tile(x2, b0, 0,   32, S2, xs + 32*S1, tid);
        __syncthreads();
        const _Float16* X1L = xs + lrow * S1;
        const _Float16* X2L = xs + 32*S1 + lrow * S2;
        const float d0 = cg[35]*c1n, d1 = cg[39]*c1n, d2 = cg[43]*c1n;
        v4f acc[12];   // [p*4 + cti]
        #pragma unroll
        for (int c = 0; c < 12; ++c) acc[c] = (v4f)0.f;
        #pragma unroll 1
        for (int tu = kh*32; tu < kh*32 + 32; ++tu) {
            const int u3 = 3 * tu;
            const _Float16 m0 = (_Float16)(d0*(float)X1L[u3]);
            const _Float16 m1 = (_Float16)(d1*(float)X1L[u3+1]);
            const _Float16 m2 = (_Float16)(d2*(float)X1L[u3+2]);
            #pragma unroll 1
            for (int q4 = 0; q4 < 4; ++q4) {
                const int t = tu*4 + q4;
                v8h xv = *(const v8h*)(X2L + 32*q4 + quad*8);
                v8h af[3];
                af[0] = xv * m0;                      // vector pk_mul
                af[1] = xv * m1;
                af[2] = xv * m2;
                const _Float16* bp = wt2 + 2752512 + (size_t)((256+t)*4) * 512 + qil;
                #pragma unroll
                for (int cti = 0; cti < 4; ++cti) {
                    v8h bf = *(const v8h*)(bp + cti * 512);
                    #pragma unroll
                    for (int p = 0; p < 3; ++p)
                        acc[p*4+cti] = __builtin_amdgcn_mfma_f32_16x16x32_f16(af[p], bf, acc[p*4+cti], 0, 0, 0);
                }
            }
        }
        PAIR_REDUCE(12)
        if (!kh) {
            #pragma unroll
            for (int i = 0; i < 4; ++i) {
                int r = b0 + rt*16 + quad*4 + i;
                #pragma unroll
                for (int p = 0; p < 3; ++p)
                    #pragma unroll
                    for (int cti = 0; cti < 4; ++cti)
                        out[(size_t)r * DIMX + 128 + (cti*16 + l16)*3 + p] = acc[p*4+cti][i];
            }
        }
        break; }
    case 5: { // (1,2,1) sec1 -> pb, K 2048 (kept chh structure: reg pressure)
        const int chh = wv >> 1;
        const int S1 = 200, S2 = 168;
        stage_tile(x1, b0, 128, 48, S1, xs, tid);
        stage_tile(x2, b0, 320, 40, S2, xs + 32*S1, tid);
        __syncthreads();
        const _Float16* X1L = xs + lrow * S1;
        const _Float16* X2L = xs + 32*S1 + lrow * S2;
        v4f acc[3][2];
        for (int p = 0; p < 3; ++p) { acc[p][0] = (v4f)0.f; acc[p][1] = (v4f)0.f; }
        #pragma unroll 1
        for (int t = 0; t < 64; ++t) {
            const int u3 = 3 * t;
            float p1[3];
            #pragma unroll
            for (int i1 = 0; i1 < 3; ++i1) p1[i1] = c1n * (float)X1L[u3 + i1];
            _Float16 yh[5][3];
            #pragma unroll
            for (int j2 = 0; j2 < 5; ++j2)
                #pragma unroll
                for (int p = 0; p < 3; ++p)
                    yh[j2][p] = (_Float16)(cg[98 + (0*5+j2)*3 + p]*p1[0]
                                         + cg[98 + (1*5+j2)*3 + p]*p1[1]
                                         + cg[98 + (2*5+j2)*3 + p]*p1[2]);
            const int col = 40 * quad;
            v8h a[5];
            #pragma unroll
            for (int q = 0; q < 5; ++q) a[q] = *(const v8h*)(X2L + col + 8*q);
            v8h af[3];
            #pragma unroll
            for (int j = 0; j < 8; ++j) {
                _Float16 s0 = (_Float16)0.f, s1 = (_Float16)0.f, s2 = (_Float16)0.f;
                #pragma unroll
                for (int j2 = 0; j2 < 5; ++j2) {
                    _Float16 x = XH(a, 5*j + j2);
                    s0 += yh[j2][0]*x; s1 += yh[j2][1]*x; s2 += yh[j2][2]*x;
                }
                af[0][j] = s0; af[1][j] = s1; af[2][j] = s2;
            }
            #pragma unroll
            for (int cti = 0; cti < 2; ++cti) {
                v8h bf = *(const v8h*)(wt2 + 2752512 + (size_t)((512+t)*4 + chh*2 + cti)*512 + qil);
                #pragma unroll
                for (int p = 0; p < 3; ++p)
                    acc[p][cti] = __builtin_amdgcn_mfma_f32_16x16x32_f16(af[p], bf, acc[p][cti], 0, 0, 0);
            }
        }
        #pragma unroll
        for (int i = 0; i < 4; ++i) {
            int r = b0 + rt*16 + quad*4 + i;
            #pragma unroll
            for (int p = 0; p < 3; ++p)
                #pragma unroll
                for (int cti = 0; cti < 2; ++cti)
                    pb[(size_t)r * DIMX + 128 + ((chh*2+cti)*16 + l16)*3 + p] = acc[p][cti][i];
        }
        break; }
    case 6: { // (2,1,1) sec1 -> pc, K 2048
        const int S1 = 168, S2 = 200;
        stage_tile(x1, b0, 320, 40, S1, xs, tid);
        stage_tile(x2, b0, 128, 48, S2, xs + 32*S1, tid);
        __syncthreads();
        const _Float16* X1L = xs + lrow * S1;
        const _Float16* X2L = xs + 32*S1 + lrow * S2;
        v4f acc[12];   // [p*4 + cti]
        #pragma unroll
        for (int c = 0; c < 12; ++c) acc[c] = (v4f)0.f;
        #pragma unroll 1
        for (int tu = kh*16; tu < kh*16 + 16; ++tu) {
            const int u5 = 5 * tu;
            float p1[5];
            #pragma unroll
            for (int i1 = 0; i1 < 5; ++i1) p1[i1] = c1n * (float)X1L[u5 + i1];
            _Float16 yh[3][3];   // per-tu: halves the CG fma count
            #pragma unroll
            for (int j2 = 0; j2 < 3; ++j2)
                #pragma unroll
                for (int p = 0; p < 3; ++p) {
                    float s = 0.f;
                    #pragma unroll
                    for (int i1 = 0; i1 < 5; ++i1)
                        s += cg[168 + (i1*3+j2)*3 + p] * p1[i1];
                    yh[j2][p] = (_Float16)s;
                }
            #pragma unroll 1
            for (int h = 0; h < 2; ++h) {
                const int t = tu*2 + h;
                const int col = 96*h + 24*quad;
                v8h a[3];
                a[0] = *(const v8h*)(X2L + col);
                a[1] = *(const v8h*)(X2L + col + 8);
                a[2] = *(const v8h*)(X2L + col + 16);
                v8h af[3];
                #pragma unroll
                for (int j = 0; j < 8; ++j) {
                    _Float16 s0 = (_Float16)0.f, s1 = (_Float16)0.f, s2 = (_Float16)0.f;
                    #pragma unroll
                    for (int j2 = 0; j2 < 3; ++j2) {
                        _Float16 x = XH(a, 3*j + j2);
                        s0 += yh[j2][0]*x; s1 += yh[j2][1]*x; s2 += yh[j2][2]*x;
                    }
                    af[0][j] = s0; af[1][j] = s1; af[2][j] = s2;
                }
                const _Float16* bp = wt2 + 2752512 + (size_t)((576+t)*4) * 512 + qil;
                #pragma unroll
                for (int cti = 0; cti < 4; ++cti) {
                    v8h bf = *(const v8h*)(bp + cti * 512);
                    #pragma unroll
                    for (int p = 0; p < 3; ++p)
                        acc[p*4+cti] = __builtin_amdgcn_mfma_f32_16x16x32_f16(af[p], bf, acc[p*4+cti], 0, 0, 0);
                }
            }
        }
        PAIR_REDUCE(12)
        if (!kh) {
            #pragma unroll
            for (int i = 0; i < 4; ++i) {
                int r = b0 + rt*16 + quad*4 + i;
                #pragma unroll
                for (int p = 0; p < 3; ++p)
                    #pragma unroll
                    for (int cti = 0; cti < 4; ++cti)
                        pc[(size_t)r * DIMX + 128 + (cti*16 + l16)*3 + p] = acc[p*4+cti][i];
            }
        }
        break; }
    case 7: { // (0,2,2) sec2 -> pa, K 4096
        const int S1 = 136, S2 = 168;
        stage_tile(x1, b0, 0,   32, S1, xs, tid);
        stage_tile(x2, b0, 320, 40, S2, xs + 32*S1, tid);
        __syncthreads();
        const _Float16* X1L = xs + lrow * S1;
        const _Float16* X2L = xs + 32*S1 + lrow * S2;
        v4f acc[10];   // [kk*2 + cti]
        #pragma unroll
        for (int c = 0; c < 10; ++c) acc[c] = (v4f)0.f;
        v8h a[5];   // t-invariant x2 fragment: hoist
        #pragma unroll
        for (int q = 0; q < 5; ++q) a[q] = *(const v8h*)(X2L + 40*quad + 8*q);
        #pragma unroll 1
        for (int t = kh*64; t < kh*64 + 64; ++t) {
            const float xu = c2n * (float)X1L[t];
            _Float16 e[5];
            #pragma unroll
            for (int kk = 0; kk < 5; ++kk) e[kk] = (_Float16)(cg[10 + 6*kk] * xu);
            v8h af[5];
            #pragma unroll
            for (int j = 0; j < 8; ++j)
                #pragma unroll
                for (int kk = 0; kk < 5; ++kk)
                    af[kk][j] = e[kk] * XH(a, 5*j + kk);   // 1x v_mul_f16 each
            const _Float16* bp = wt2 + 4063232 + (size_t)(t*2) * 512 + qil;
            #pragma unroll
            for (int cti = 0; cti < 2; ++cti) {
                v8h bf = *(const v8h*)(bp + cti * 512);
                #pragma unroll
                for (int kk = 0; kk < 5; ++kk)
                    acc[kk*2+cti] = __builtin_amdgcn_mfma_f32_16x16x32_f16(af[kk], bf, acc[kk*2+cti], 0, 0, 0);
            }
        }
        PAIR_REDUCE(10)
        if (!kh) {
            #pragma unroll
            for (int i = 0; i < 4; ++i) {
                int r = b0 + rt*16 + quad*4 + i;
                #pragma unroll
                for (int kk = 0; kk < 5; ++kk)
                    #pragma unroll
                    for (int cti = 0; cti < 2; ++cti)
                        pa[(size_t)r * DIMX + 320 + (cti*16 + l16)*5 + kk] = acc[kk*2+cti][i];
            }
        }
        break; }
    case 8: { // (1,1,2) sec2 -> pb, K 4096
        const int S = 200;
        stage_tile(x1, b0, 128, 48, S, xs, tid);
        stage_tile(x2, b0, 128, 48, S, xs + 32*S, tid);
        __syncthreads();
        const _Float16* X1L = xs + lrow * S;
        const _Float16* X2L = xs + 32*S + lrow * S;
        v4f acc[10];   // [kk*2 + cti]
        #pragma unroll
        for (int c = 0; c < 10; ++c) acc[c] = (v4f)0.f;
        #pragma unroll 1
        for (int tu = kh*32; tu < kh*32 + 32; ++tu) {
            const int u3 = 3 * tu;
            float p1[3];
            #pragma unroll
            for (int i1 = 0; i1 < 3; ++i1) p1[i1] = c2n * (float)X1L[u3 + i1];
            _Float16 yh[3][5];   // per-tu
            #pragma unroll
            for (int j2 = 0; j2 < 3; ++j2)
                #pragma unroll
                for (int kk = 0; kk < 5; ++kk)
                    yh[j2][kk] = (_Float16)(cg[53 + (0*3+j2)*5 + kk]*p1[0]
                                          + cg[53 + (1*3+j2)*5 + kk]*p1[1]
                                          + cg[53 + (2*3+j2)*5 + kk]*p1[2]);
            #pragma unroll 1
            for (int h = 0; h < 2; ++h) {
                const int t = tu*2 + h;
                const int col = 96*h + 24*quad;
                v8h a[3];
                a[0] = *(const v8h*)(X2L + col);
                a[1] = *(const v8h*)(X2L + col + 8);
                a[2] = *(const v8h*)(X2L + col + 16);
                v8h af[5];
                #pragma unroll
                for (int j = 0; j < 8; ++j) {
                    _Float16 s[5] = {(_Float16)0.f, (_Float16)0.f, (_Float16)0.f,
                                     (_Float16)0.f, (_Float16)0.f};
                    #pragma unroll
                    for (int j2 = 0; j2 < 3; ++j2) {
                        _Float16 x = XH(a, 3*j + j2);
                        #pragma unroll
                        for (int kk = 0; kk < 5; ++kk) s[kk] += yh[j2][kk] * x;
                    }
                    #pragma unroll
                    for (int kk = 0; kk < 5; ++kk) af[kk][j] = s[kk];
                }
                const _Float16* bp = wt2 + 4063232 + (size_t)((128+t)*2) * 512 + qil;
                #pragma unroll
                for (int cti = 0; cti < 2; ++cti) {
                    v8h bf = *(const v8h*)(bp + cti * 512);
                    #pragma unroll
                    for (int kk = 0; kk < 5; ++kk)
                        acc[kk*2+cti] = __builtin_amdgcn_mfma_f32_16x16x32_f16(af[kk], bf, acc[kk*2+cti], 0, 0, 0);
                }
            }
        }
        PAIR_REDUCE(10)
        if (!kh) {
            #pragma unroll
            for (int i = 0; i < 4; ++i) {
                int r = b0 + rt*16 + quad*4 + i;
                #pragma unroll
                for (int kk = 0; kk < 5; ++kk)
                    #pragma unroll
                    for (int cti = 0; cti < 2; ++cti)
                        pb[(size_t)r * DIMX + 320 + (cti*16 + l16)*5 + kk] = acc[kk*2+cti][i];
            }
        }
        break; }
    case 9: { // (2,0,2) sec2 -> out, K 4096
        const int S1 = 168, S2 = 136;
        stage_tile(x1, b0, 320, 40, S1, xs, tid);
        stage_tile(x2, b0, 0,   32, S2, xs + 32*S1, tid);
        __syncthreads();
        const _Float16* X1L = xs + lrow * S1;
        const _Float16* X2L = xs + 32*S1 + lrow * S2;
        v4f acc[10];   // [kk*2 + cti]
        #pragma unroll
        for (int c = 0; c < 10; ++c) acc[c] = (v4f)0.f;
        #pragma unroll 1
        for (int tu = kh*16; tu < kh*16 + 16; ++tu) {
            const int u5 = 5 * tu;
            _Float16 m[5];
            #pragma unroll
            for (int kk = 0; kk < 5; ++kk)
                m[kk] = (_Float16)(cg[143 + 6*kk] * c2n * (float)X1L[u5 + kk]);
            #pragma unroll 1
            for (int q4 = 0; q4 < 4; ++q4) {
                const int t = tu*4 + q4;
                v8h xv = *(const v8h*)(X2L + 32*q4 + quad*8);
                v8h af[5];
                #pragma unroll
                for (int kk = 0; kk < 5; ++kk) af[kk] = xv * m[kk];  // vector pk_mul
                const _Float16* bp = wt2 + 4063232 + (size_t)((256+t)*2) * 512 + qil;
                #pragma unroll
                for (int cti = 0; cti < 2; ++cti) {
                    v8h bf = *(const v8h*)(bp + cti * 512);
                    #pragma unroll
                    for (int kk = 0; kk < 5; ++kk)
                        acc[kk*2+cti] = __builtin_amdgcn_mfma_f32_16x16x32_f16(af[kk], bf, acc[kk*2+cti], 0, 0, 0);
                }
            }
        }
        PAIR_REDUCE(10)
        if (!kh) {
            #pragma unroll
            for (int i = 0; i < 4; ++i) {
                int r = b0 + rt*16 + quad*4 + i;
                #pragma unroll
                for (int kk = 0; kk < 5; ++kk)
                    #pragma unroll
                    for (int cti = 0; cti < 2; ++cti)
                        out[(size_t)r * DIMX + 320 + (cti*16 + l16)*5 + kk] = acc[kk*2+cti][i];
            }
        }
        break; }
    default: { // case 10: (2,2,2) sec2 -> pc, K 1024 (kept chh structure)
        const int chh = wv >> 1;
        const int S = 168;
        stage_tile(x1, b0, 320, 40, S, xs, tid);
        stage_tile(x2, b0, 320, 40, S, xs + 32*S, tid);
        __syncthreads();
        const _Float16* X1L = xs + lrow * S;
        const _Float16* X2L = xs + 32*S + lrow * S;
        v4f acc[5]; for (int p = 0; p < 5; ++p) acc[p] = (v4f)0.f;
        #pragma unroll 1
        for (int t = 0; t < 32; ++t) {
            const int u5 = 5 * t;
            float p1[5];
            #pragma unroll
            for (int i1 = 0; i1 < 5; ++i1) p1[i1] = c2n * (float)X1L[u5 + i1];
            _Float16 yh[5][5];
            #pragma unroll
            for (int j2 = 0; j2 < 5; ++j2)
                #pragma unroll
                for (int kk = 0; kk < 5; ++kk) {
                    float s = 0.f;
                    #pragma unroll
                    for (int i1 = 0; i1 < 5; ++i1)
                        s += cg[238 + (i1*5+j2)*5 + kk] * p1[i1];
                    yh[j2][kk] = (_Float16)s;
                }
            const int col = 40 * quad;
            v8h a[5];
            #pragma unroll
            for (int q = 0; q < 5; ++q) a[q] = *(const v8h*)(X2L + col + 8*q);
            v8h af[5];
            #pragma unroll
            for (int j = 0; j < 8; ++j) {
                _Float16 s[5] = {(_Float16)0.f, (_Float16)0.f, (_Float16)0.f,
                                 (_Float16)0.f, (_Float16)0.f};
                #pragma unroll
                for (int j2 = 0; j2 < 5; ++j2) {
                    _Float16 x = XH(a, 5*j + j2);
                    #pragma unroll
                    for (int kk = 0; kk < 5; ++kk) s[kk] += yh[j2][kk] * x;
                }
                #pragma unroll
                for (int kk = 0; kk < 5; ++kk) af[kk][j] = s[kk];
            }
            v8h bf = *(const v8h*)(wt2 + 4063232 + (size_t)((384+t)*2 + chh)*512 + qil);
            #pragma unroll
            for (int kk = 0; kk < 5; ++kk)
                acc[kk] = __builtin_amdgcn_mfma_f32_16x16x32_f16(af[kk], bf, acc[kk], 0, 0, 0);
        }
        #pragma unroll
        for (int i = 0; i < 4; ++i) {
            int r = b0 + rt*16 + quad*4 + i;
            #pragma unroll
            for (int kk = 0; kk < 5; ++kk)
                pc[(size_t)r * DIMX + 320 + (chh*16 + l16)*5 + kk] = acc[kk][i];
        }
        break; }
    }
}

// out += pa + pb + pc (all buffers fully populated, column-disjoint per path).
// 983040 float4, 3840 blocks.
__global__ void add3_kernel(float4* __restrict__ o, const float4* __restrict__ pa,
                            const float4* __restrict__ pb, const float4* __restrict__ pc) {
    size_t i = (size_t)blockIdx.x * 256 + threadIdx.x;
    float4 r = o[i], a = pa[i], b = pb[i], c = pc[i];
    r.x += a.x + b.x + c.x; r.y += a.y + b.y + c.y;
    r.z += a.z + b.z + c.z; r.w += a.w + b.w + c.w;
    o[i] = r;
}

// ---------------------------------------------------------------------------
// Fallback (round-6 kernel, verified; fp16 port): used when ws is small.
// ---------------------------------------------------------------------------
template<bool UW>
__global__ __launch_bounds__(256, 2) void tp_fb(
    const float* __restrict__ x1, const float* __restrict__ x2,
    const float* __restrict__ w, const _Float16* __restrict__ wt2,
    const float* __restrict__ cg, float* __restrict__ out)
{
    __shared__ _Float16 x1s[32 * 488];
    __shared__ _Float16 x2s[32 * 488];
    const int tid  = threadIdx.x;
    const int lane = tid & 63;
    const int wv   = tid >> 6;
    const int quad = lane >> 4;
    const int l16  = lane & 15;
    const int sec  = blockIdx.x % 3;
    const int bt   = blockIdx.x / 3;
    const int b0   = bt * 32;

    for (int c = tid; c < 3840; c += 256) {
        int row = c / 120, ch = c - row * 120;
        float4 v1 = *(const float4*)(x1 + (size_t)(b0 + row) * DIMX + ch * 4);
        float4 v2 = *(const float4*)(x2 + (size_t)(b0 + row) * DIMX + ch * 4);
        v4h p1, p2;
        p1[0]=(_Float16)v1.x; p1[1]=(_Float16)v1.y; p1[2]=(_Float16)v1.z; p1[3]=(_Float16)v1.w;
        p2[0]=(_Float16)v2.x; p2[1]=(_Float16)v2.y; p2[2]=(_Float16)v2.z; p2[3]=(_Float16)v2.w;
        *(v4h*)(&x1s[row * 488 + ch * 4]) = p1;
        *(v4h*)(&x2s[row * 488 + ch * 4]) = p2;
    }
    __syncthreads();

    const int rt  = wv & 1;
    const int chh = wv >> 1;
    const int lrow = rt * 16 + l16;
    const _Float16* X1L = x1s + lrow * 488;
    const _Float16* X2L = x2s + lrow * 488;

    if (sec == 0) {
        const float c0 = sqrtf(1.0f / 21504.0f);
        v4f acc[4];
        #pragma unroll
        for (int b = 0; b < 4; ++b) acc[b] = (v4f)0.f;
        const _Float16* wtw = wt2 + (size_t)(quad * 16 + l16) * 8;
        #pragma unroll 1
        for (int t = 0; t < 336; ++t) {
            const int kt = t * 64;
            v8h af[2];
            if (kt < 16384) {
                const int u = kt >> 7;
                const float s = cg[0] * c0 * (float)X1L[u];
                #pragma unroll
                for (int ks = 0; ks < 2; ++ks) {
                    v8h xv = *(const v8h*)(X2L + (kt & 127) + ks * 32 + quad * 8);
                    #pragma unroll
                    for (int j = 0; j < 8; ++j) af[ks][j] = (_Float16)(s * (float)xv[j]);
                }
            } else if (kt < 20480) {
                const int u = (kt - 16384) >> 6;
                const float m0 = cg[44]*c0*(float)X1L[128+3*u];
                const float m1 = cg[48]*c0*(float)X1L[128+3*u+1];
                const float m2 = cg[52]*c0*(float)X1L[128+3*u+2];
                #pragma unroll
                for (int ks = 0; ks < 2; ++ks) {
                    const int col = 128 + 3 * (ks * 32 + quad * 8);
                    v8h xv[3];
                    xv[0] = *(const v8h*)(X2L + col);
                    xv[1] = *(const v8h*)(X2L + col + 8);
                    xv[2] = *(const v8h*)(X2L + col + 16);
                    #pragma unroll
                    for (int j = 0; j < 8; ++j)
                        af[ks][j] = (_Float16)(m0*XE(xv,3*j) + m1*XE(xv,3*j+1) + m2*XE(xv,3*j+2));
                }
            } else {
                #pragma unroll
                for (int ks = 0; ks < 2; ++ks) {
                    const int u = ((kt - 20480) >> 5) + ks;
                    float m[5];
                    #pragma unroll
                    for (int k = 0; k < 5; ++k)
                        m[k] = cg[213 + 6*k] * c0 * (float)X1L[320 + 5*u + k];
                    const int col = 320 + 40 * quad;
                    v8h xv[5];
                    #pragma unroll
                    for (int q = 0; q < 5; ++q) xv[q] = *(const v8h*)(X2L + col + 8*q);
                    #pragma unroll
                    for (int j = 0; j < 8; ++j) {
                        float a = 0.f;
                        #pragma unroll
                        for (int k = 0; k < 5; ++k) a += m[k] * XE(xv, 5*j+k);
                        af[ks][j] = (_Float16)a;
                    }
                }
            }
            #pragma unroll
            for (int ks = 0; ks < 2; ++ks) {
                const int kblk = (kt >> 5) + ks;
                #pragma unroll
                for (int ct = 0; ct < 4; ++ct) {
                    v8h bf;
                    if (UW) {
                        bf = *(const v8h*)(wtw + (size_t)(kblk * 8 + chh * 4 + ct) * 512);
                    } else {
                        int rb, pb;
                        if (kt < 16384)      { rb = 0;     pb = 0; }
                        else if (kt < 20480) { rb = 16384; pb = 3276800; }
                        else                 { rb = 20480; pb = 4325376; }
                        const float* src = w + pb + (size_t)(kt + ks*32 + quad*8 - rb) * 128
                                           + (chh*4 + ct)*16 + l16;
                        #pragma unroll
                        for (int j = 0; j < 8; ++j) bf[j] = (_Float16)src[(size_t)j * 128];
                    }
                    acc[ct] = __builtin_amdgcn_mfma_f32_16x16x32_f16(af[ks], bf, acc[ct], 0, 0, 0);
                }
            }
        }
        #pragma unroll
        for (int i = 0; i < 4; ++i) {
            const int r = b0 + rt*16 + quad*4 + i;
            float* orow = out + (size_t)r * DIMX;
            #pragma unroll
            for (int ct = 0; ct < 4; ++ct) orow[chh*64 + ct*16 + l16] = acc[ct][i];
        }
    } else if (sec == 1) {
        const float c1 = sqrtf(3.0f / 20480.0f);
        v4f acc[3][2];
        #pragma unroll
        for (int p = 0; p < 3; ++p) { acc[p][0] = (v4f)0.f; acc[p][1] = (v4f)0.f; }
        const _Float16* wtw = wt2 + 2752512 + (size_t)(quad * 16 + l16) * 8;
        #pragma unroll 1
        for (int t = 0; t < 640; ++t) {
            const int kt = t * 32;
            v8h af[3];
            if (kt < 8192) {
                const int u = kt >> 6;
                const float xv1 = (float)X1L[u];
                const float e0 = cg[1]*c1*xv1, e1 = cg[5]*c1*xv1, e2 = cg[9]*c1*xv1;
                const int col = 128 + 3 * ((kt & 63) + quad * 8);
                v8h xv[3];
                xv[0] = *(const v8h*)(X2L + col);
                xv[1] = *(const v8h*)(X2L + col + 8);
                xv[2] = *(const v8h*)(X2L + col + 16);
                #pragma unroll
                for (int j = 0; j < 8; ++j) {
                    af[0][j] = (_Float16)(e0 * XE(xv, 3*j));
                    af[1][j] = (_Float16)(e1 * XE(xv, 3*j+1));
                    af[2][j] = (_Float16)(e2 * XE(xv, 3*j+2));
                }
            } else if (kt < 16384) {
                const int q0 = kt - 8192;
                const int u = q0 >> 7;
                const float m0 = cg[35]*c1*(float)X1L[128+3*u];
                const float m1 = cg[39]*c1*(float)X1L[128+3*u+1];
                const float m2 = cg[43]*c1*(float)X1L[128+3*u+2];
                v8h xv = *(const v8h*)(X2L + (q0 & 127) + quad * 8);
                #pragma unroll
                for (int j = 0; j < 8; ++j) {
                    float x = (float)xv[j];
                    af[0][j] = (_Float16)(m0 * x);
                    af[1][j] = (_Float16)(m1 * x);
                    af[2][j] = (_Float16)(m2 * x);
                }
            } else if (kt < 18432) {
                const int u = (kt - 16384) >> 5;
                float p1[3];
                #pragma unroll
                for (int i1 = 0; i1 < 3; ++i1) p1[i1] = c1 * (float)X1L[128 + 3*u + i1];
                float y[5][3];
                #pragma unroll
                for (int j2 = 0; j2 < 5; ++j2)
                    #pragma unroll
                    for (int k = 0; k < 3; ++k)
                        y[j2][k] = cg[98 + (0*5+j2)*3 + k]*p1[0]
                                 + cg[98 + (1*5+j2)*3 + k]*p1[1]
                                 + cg[98 + (2*5+j2)*3 + k]*p1[2];
                const int col = 320 + 40 * quad;
                v8h xv[5];
                #pragma unroll
                for (int q = 0; q < 5; ++q) xv[q] = *(const v8h*)(X2L + col + 8*q);
                #pragma unroll
                for (int j = 0; j < 8; ++j) {
                    float a0 = 0.f, a1 = 0.f, a2 = 0.f;
                    #pragma unroll
                    for (int j2 = 0; j2 < 5; ++j2) {
                        float x = XE(xv, 5*j + j2);
                        a0 += y[j2][0]*x; a1 += y[j2][1]*x; a2 += y[j2][2]*x;
                    }
                    af[0][j] = (_Float16)a0; af[1][j] = (_Float16)a1; af[2][j] = (_Float16)a2;
                }
            } else {
                const int q0 = kt - 18432;
                const int u = q0 >> 6;
                float p1[5];
                #pragma unroll
                for (int i1 = 0; i1 < 5; ++i1) p1[i1] = c1 * (float)X1L[320 + 5*u + i1];
                float y[3][3];
                #pragma unroll
                for (int j2 = 0; j2 < 3; ++j2)
                    #pragma unroll
                    for (int k = 0; k < 3; ++k) {
                        float s = 0.f;
                        #pragma unroll
                        for (int i1 = 0; i1 < 5; ++i1)
                            s += cg[168 + (i1*3+j2)*3 + k] * p1[i1];
                        y[j2][k] = s;
                    }
                const int col = 128 + 3 * ((q0 & 63) + quad * 8);
                v8h xv[3];
                xv[0] = *(const v8h*)(X2L + col);
                xv[1] = *(const v8h*)(X2L + col + 8);
                xv[2] = *(const v8h*)(X2L + col + 16);
                #pragma unroll
                for (int j = 0; j < 8; ++j) {
                    float a0 = 0.f, a1 = 0.f, a2 = 0.f;
                    #pragma unroll
                    for (int j2 = 0; j2 < 3; ++j2) {
                        float x = XE(xv, 3*j + j2);
                        a0 += y[j2][0]*x; a1 += y[j2][1]*x; a2 += y[j2][2]*x;
                    }
                    af[0][j] = (_Float16)a0; af[1][j] = (_Float16)a1; af[2][j] = (_Float16)a2;
                }
            }
            #pragma unroll
            for (int cti = 0; cti < 2; ++cti) {
                const int nblk = chh * 2 + cti;
                v8h bf;
                if (UW) {
                    bf = *(const v8h*)(wtw + (size_t)(t * 4 + nblk) * 512);
                } else {
                    int rb, pb;
                    if (kt < 8192)       { rb = 0;     pb = 2097152; }
                    else if (kt < 16384) { rb = 8192;  pb = 2752512; }
                    else if (kt < 18432) { rb = 16384; pb = 3932160; }
                    else                 { rb = 18432; pb = 4194304; }
                    const float* src = w + pb + (size_t)(kt + quad*8 - rb) * 64 + nblk*16 + l16;
                    #pragma unroll
                    for (int j = 0; j < 8; ++j) bf[j] = (_Float16)src[(size_t)j * 64];
                }
                #pragma unroll
                for (int p = 0; p < 3; ++p)
                    acc[p][cti] = __builtin_amdgcn_mfma_f32_16x16x32_f16(af[p], bf, acc[p][cti], 0, 0, 0);
            }
        }
        #pragma unroll
        for (int i = 0; i < 4; ++i) {
            const int r = b0 + rt*16 + quad*4 + i;
            float* orow = out + (size_t)r * DIMX;
            #pragma unroll
            for (int p = 0; p < 3; ++p)
                #pragma unroll
                for (int cti = 0; cti < 2; ++cti)
                    orow[128 + ((chh*2 + cti)*16 + l16) * 3 + p] = acc[p][cti][i];
        }
    } else {
        const float c2 = sqrtf(5.0f / 13312.0f);
        v4f acc[5];
        #pragma unroll
        for (int p = 0; p < 5; ++p) acc[p] = (v4f)0.f;
        const _Float16* wtw = wt2 + 4063232 + (size_t)(quad * 16 + l16) * 8;
        #pragma unroll 1
        for (int t = 0; t < 416; ++t) {
            const int kt = t * 32;
            v8h af[5];
            if (kt < 4096) {
                const int u = kt >> 5;
                const float s = c2 * (float)X1L[u];
                float e[5];
                #pragma unroll
                for (int k = 0; k < 5; ++k) e[k] = cg[10 + 6*k] * s;
                const int col = 320 + 40 * quad;
                v8h xv[5];
                #pragma unroll
                for (int q = 0; q < 5; ++q) xv[q] = *(const v8h*)(X2L + col + 8*q);
                #pragma unroll
                for (int j = 0; j < 8; ++j)
                    #pragma unroll
                    for (int k = 0; k < 5; ++k)
                        af[k][j] = (_Float16)(e[k] * XE(xv, 5*j + k));
            } else if (kt < 8192) {
                const int q0 = kt - 4096;
                const int u = q0 >> 6;
                float p1[3];
                #pragma unroll
                for (int i1 = 0; i1 < 3; ++i1) p1[i1] = c2 * (float)X1L[128 + 3*u + i1];
                float y[3][5];
                #pragma unroll
                for (int j2 = 0; j2 < 3; ++j2)
                    #pragma unroll
                    for (int k = 0; k < 5; ++k)
                        y[j2][k] = cg[53 + (0*3+j2)*5 + k]*p1[0]
                                 + cg[53 + (1*3+j2)*5 + k]*p1[1]
                                 + cg[53 + (2*3+j2)*5 + k]*p1[2];
                const int col = 128 + 3 * ((q0 & 63) + quad * 8);
                v8h xv[3];
                xv[0] = *(const v8h*)(X2L + col);
                xv[1] = *(const v8h*)(X2L + col + 8);
                xv[2] = *(const v8h*)(X2L + col + 16);
                #pragma unroll
                for (int j = 0; j < 8; ++j) {
                    float a[5] = {0.f, 0.f, 0.f, 0.f, 0.f};
                    #pragma unroll
                    for (int j2 = 0; j2 < 3; ++j2) {
                        float x = XE(xv, 3*j + j2);
                        #pragma unroll
                        for (int k = 0; k < 5; ++k) a[k] += y[j2][k] * x;
                    }
                    #pragma unroll
                    for (int k = 0; k < 5; ++k) af[k][j] = (_Float16)a[k];
                }
            } else if (kt < 12288) {
                const int q0 = kt - 8192;
                const int u = q0 >> 7;
                float m[5];
                #pragma unroll
                for (int k = 0; k < 5; ++k)
                    m[k] = cg[143 + 6*k] * c2 * (float)X1L[320 + 5*u + k];
                v8h xv = *(const v8h*)(X2L + (q0 & 127) + quad * 8);
                #pragma unroll
                for (int j = 0; j < 8; ++j) {
                    float x = (float)xv[j];
                    #pragma unroll
                    for (int k = 0; k < 5; ++k) af[k][j] = (_Float16)(m[k] * x);
                }
            } else {
                const int u = (kt - 12288) >> 5;
                float p1[5];
                #pragma unroll
                for (int i1 = 0; i1 < 5; ++i1) p1[i1] = c2 * (float)X1L[320 + 5*u + i1];
                float y[5][5];
                #pragma unroll
                for (int j2 = 0; j2 < 5; ++j2)
                    #pragma unroll
                    for (int k = 0; k < 5; ++k) {
                        float s = 0.f;
                        #pragma unroll
                        for (int i1 = 0; i1 < 5; ++i1)
                            s += cg[238 + (i1*5+j2)*5 + k] * p1[i1];
                        y[j2][k] = s;
                    }
                const int col = 320 + 40 * quad;
                v8h xv[5];
                #pragma unroll
                for (int q = 0; q < 5; ++q) xv[q] = *(const v8h*)(X2L + col + 8*q);
                #pragma unroll
                for (int j = 0; j < 8; ++j) {
                    float a[5] = {0.f, 0.f, 0.f, 0.f, 0.f};
                    #pragma unroll
                    for (int j2 = 0; j2 < 5; ++j2) {
                        float x = XE(xv, 5*j + j2);
                        #pragma unroll
                        for (int k = 0; k < 5; ++k) a[k] += y[j2][k] * x;
                    }
                    #pragma unroll
                    for (int k = 0; k < 5; ++k) af[k][j] = (_Float16)a[k];
                }
            }
            {
                v8h bf;
                if (UW) {
                    bf = *(const v8h*)(wtw + (size_t)(t * 2 + chh) * 512);
                } else {
                    int rb, pb;
                    if (kt < 4096)       { rb = 0;     pb = 2621440; }
                    else if (kt < 8192)  { rb = 4096;  pb = 3801088; }
                    else if (kt < 12288) { rb = 8192;  pb = 4063232; }
                    else                 { rb = 12288; pb = 4456448; }
                    const float* src = w + pb + (size_t)(kt + quad*8 - rb) * 32 + chh*16 + l16;
                    #pragma unroll
                    for (int j = 0; j < 8; ++j) bf[j] = (_Float16)src[(size_t)j * 32];
                }
                #pragma unroll
                for (int k = 0; k < 5; ++k)
                    acc[k] = __builtin_amdgcn_mfma_f32_16x16x32_f16(af[k], bf, acc[k], 0, 0, 0);
            }
        }
        #pragma unroll
        for (int i = 0; i < 4; ++i) {
            const int r = b0 + rt*16 + quad*4 + i;
            float* orow = out + (size_t)r * DIMX;
            #pragma unroll
            for (int k = 0; k < 5; ++k)
                orow[320 + (chh*16 + l16) * 5 + k] = acc[k][i];
        }
    }
}

extern "C" void kernel_launch(void* const* d_in, const int* in_sizes, int n_in,
                              void* d_out, int out_size, void* d_ws, size_t ws_size,
                              hipStream_t stream) {
    const float* x1 = (const float*)d_in[0];
    const float* x2 = (const float*)d_in[1];
    const float* wt_f = (const float*)d_in[2];
    float* out = (float*)d_out;
    (void)in_sizes; (void)n_in; (void)out_size;

    static float h_cg[363];
    static bool h_cg_done = false;
    if (!h_cg_done) { build_cg_host(h_cg); h_cg_done = true; }

    const size_t WT_BYTES = (size_t)4489216 * 2;                 // 8,978,432
    const size_t CG_PAD   = 4096;
    const size_t PART     = (size_t)8192 * DIMX * 4;             // 15,728,640
    const size_t PA_OFF   = WT_BYTES + CG_PAD;
    const size_t NEED     = PA_OFF + 3 * PART;                   // 56,168,448

    float*    cgp = (float*)((char*)d_ws + WT_BYTES);
    _Float16* wtp = (_Float16*)d_ws;
    float*    pa  = (float*)((char*)d_ws + PA_OFF);
    float*    pb  = (float*)((char*)d_ws + PA_OFF + PART);
    float*    pc  = (float*)((char*)d_ws + PA_OFF + 2 * PART);

    if (ws_size >= NEED) {
        hipMemcpyAsync(cgp, h_cg, sizeof(h_cg), hipMemcpyHostToDevice, stream);
        wt2_kernel<<<dim3(2192), dim3(256), 0, stream>>>(wt_f, wtp);
        tp_path<<<dim3(3072), dim3(256), 0, stream>>>(x1, x2, wtp, cgp, out, pa, pb, pc);
        add3_kernel<<<dim3(3840), dim3(256), 0, stream>>>(
            (float4*)out, (const float4*)pa, (const float4*)pb, (const float4*)pc);
    } else if (ws_size >= WT_BYTES + CG_PAD) {
        hipMemcpyAsync(cgp, h_cg, sizeof(h_cg), hipMemcpyHostToDevice, stream);
        wt2_kernel<<<dim3(2192), dim3(256), 0, stream>>>(wt_f, wtp);
        tp_fb<true><<<dim3(768), dim3(256), 0, stream>>>(x1, x2, wt_f, wtp, cgp, out);
    } else {
        float* cgs = (float*)d_ws;
        hipMemcpyAsync(cgs, h_cg, sizeof(h_cg), hipMemcpyHostToDevice, stream);
        tp_fb<false><<<dim3(768), dim3(256), 0, stream>>>(x1, x2, wt_f, (const _Float16*)d_ws, cgs, out);
    }
}

// Round 6
// 316.547 us; speedup vs baseline: 1.7493x; 1.7493x over previous
//
#include <hip/hip_runtime.h>
#include <math.h>

#define DIMX 480

typedef float v4f __attribute__((ext_vector_type(4)));
typedef _Float16 v8h __attribute__((ext_vector_type(8)));
typedef _Float16 v4h __attribute__((ext_vector_type(4)));

// ---------------------------------------------------------------------------
// CG tables, computed on HOST exactly per the reference (verified r1-r6; host
// port of the former device cg_init kernel, removed to save a serial launch).
//  0:(0,0,0) 0   1:(0,1,1) 1    2:(0,2,2) 10   3:(1,0,1) 35   4:(1,1,0) 44
//  5:(1,1,2) 53  6:(1,2,1) 98   7:(2,0,2) 143  8:(2,1,1) 168  9:(2,2,0) 213
// 10:(2,2,2) 238  total 363
// ---------------------------------------------------------------------------
// LPT dispatch order over 12 units (longest first) + same-path grouping for
// L2 locality. Unit 11 = second K-half of path 0 (writes pc cols 0..128).
__constant__ int c_order[12] = {8,5,10,3,4,7,9,0,11,6,1,2};

struct hcplx { double re, im; };
static inline hcplx hcmul(hcplx a, hcplx b) {
    return { a.re*b.re - a.im*b.im, a.re*b.im + a.im*b.re };
}
static double hdfact(int n) { double r = 1.0; for (int i = 2; i <= n; ++i) r *= (double)i; return r; }

static double hsu2cg(int j1, int j2, int j3, int m1, int m2) {
    int m3 = m1 + m2;
    if (m3 < -j3 || m3 > j3) return 0.0;
    double pref = (2.0*j3 + 1.0)
        * hdfact(j3 + j1 - j2) * hdfact(j3 - j1 + j2) * hdfact(j1 + j2 - j3)
        / hdfact(j1 + j2 + j3 + 1)
        * hdfact(j3 + m3) * hdfact(j3 - m3) * hdfact(j1 - m1) * hdfact(j1 + m1)
        * hdfact(j2 - m2) * hdfact(j2 + m2);
    pref = sqrt(pref);
    double s = 0.0;
    for (int k = 0; k <= j1 + j2 - j3; ++k) {
        if (j1 - m1 - k < 0 || j2 + m2 - k < 0 ||
            j3 - j2 + m1 + k < 0 || j3 - j1 - m2 + k < 0) continue;
        double d = hdfact(k) * hdfact(j1 + j2 - j3 - k) * hdfact(j1 - m1 - k)
                 * hdfact(j2 + m2 - k) * hdfact(j3 - j2 + m1 + k) * hdfact(j3 - j1 - m2 + k);
        s += ((k & 1) ? -1.0 : 1.0) / d;
    }
    return pref * s;
}

static hcplx hQval(int l, int mi, int ri) {
    const double is2 = 0.70710678118654752440;
    int m = mi - l;
    hcplx q = {0.0, 0.0};
    if (m < 0) {
        if (ri == l - m)       q = { is2, 0.0 };
        else if (ri == l + m)  q = { 0.0, -is2 };
    } else if (m == 0) {
        if (ri == l)           q = { 1.0, 0.0 };
    } else {
        double s = (m & 1) ? -1.0 : 1.0;
        if (ri == l + m)       q = { s * is2, 0.0 };
        else if (ri == l - m)  q = { 0.0, s * is2 };
    }
    int ph = l & 3;
    hcplx r;
    if (ph == 0)      r = q;
    else if (ph == 1) r = {  q.im, -q.re };
    else if (ph == 2) r = { -q.re, -q.im };
    else              r = { -q.im,  q.re };
    return r;
}

static void build_cg_host(float* cgout) {
    static const int pl[11][3] = {
        {0,0,0},{0,1,1},{0,2,2},{1,0,1},{1,1,0},{1,1,2},
        {1,2,1},{2,0,2},{2,1,1},{2,2,0},{2,2,2}};
    static const int cgo[11] = {0,1,10,35,44,53,98,143,168,213,238};
    for (int p = 0; p < 11; ++p) {
        int l1 = pl[p][0], l2 = pl[p][1], l3 = pl[p][2];
        int D2 = 2*l2 + 1, D3 = 2*l3 + 1;
        int D = (2*l1 + 1) * D2 * D3;
        double vals[125];
        double ss = 0.0;
        for (int e = 0; e < D; ++e) {
            int j  = e / (D2 * D3);
            int l_ = (e / D3) % D2;
            int n  = e % D3;
            double val = 0.0;
            for (int m1 = -l1; m1 <= l1; ++m1)
                for (int m2 = -l2; m2 <= l2; ++m2) {
                    int m3 = m1 + m2;
                    if (m3 < -l3 || m3 > l3) continue;
                    double cgv = hsu2cg(l1, l2, l3, m1, m2);
                    if (cgv == 0.0) continue;
                    hcplx t = hcmul(hcmul(hQval(l1, l1 + m1, j), hQval(l2, l2 + m2, l_)),
                                    hQval(l3, l3 + m3, n));
                    val += t.re * cgv;
                }
            vals[e] = val; ss += val * val;
        }
        double nrm = sqrt(ss);
        for (int e = 0; e < D; ++e) cgout[cgo[p] + e] = (float)(vals[e] / nrm);
    }
}

// ---------------------------------------------------------------------------
// Wt swizzle: wt2 holds fp16 B-fragments in wave-coalesced order (r6 layout).
// chunk cc = (kblk*(N/16) + nblk)*64 + quad*16 + l ; elem j ->
// Wt[n = nblk*16+l][k = kblk*32 + quad*8 + j].
// sec offs (elems): 0 / 2752512 / 4063232 ; total 4489216.
// ---------------------------------------------------------------------------
__global__ __launch_bounds__(256) void wt2_kernel(const float* __restrict__ w,
                                                  _Float16* __restrict__ wt2) {
    int c = blockIdx.x * 256 + threadIdx.x;
    int sec, cc;
    if (c < 344064)      { sec = 0; cc = c; }
    else if (c < 507904) { sec = 1; cc = c - 344064; }
    else                 { sec = 2; cc = c - 507904; }
    int l = cc & 15, quad = (cc >> 4) & 3;
    int nblk, kblk, N; size_t soff;
    if (sec == 0)      { nblk = (cc >> 6) & 7; kblk = cc >> 9; N = 128; soff = 0; }
    else if (sec == 1) { nblk = (cc >> 6) & 3; kblk = cc >> 8; N = 64;  soff = 2752512; }
    else               { nblk = (cc >> 6) & 1; kblk = cc >> 7; N = 32;  soff = 4063232; }
    int n = nblk * 16 + l;
    int k = kblk * 32 + quad * 8;
    int rb, pb;
    if (sec == 0) {
        if (k < 16384)      { rb = 0;     pb = 0; }
        else if (k < 20480) { rb = 16384; pb = 3276800; }
        else                { rb = 20480; pb = 4325376; }
    } else if (sec == 1) {
        if (k < 8192)       { rb = 0;     pb = 2097152; }
        else if (k < 16384) { rb = 8192;  pb = 2752512; }
        else if (k < 18432) { rb = 16384; pb = 3932160; }
        else                { rb = 18432; pb = 4194304; }
    } else {
        if (k < 4096)       { rb = 0;     pb = 2621440; }
        else if (k < 8192)  { rb = 4096;  pb = 3801088; }
        else if (k < 12288) { rb = 8192;  pb = 4063232; }
        else                { rb = 12288; pb = 4456448; }
    }
    const float* src = w + pb + (size_t)(k - rb) * N + n;
    v8h o;
    #pragma unroll
    for (int j = 0; j < 8; ++j) o[j] = (_Float16)src[(size_t)j * N];
    *(v8h*)(&wt2[soff + (size_t)cc * 8]) = o;
}

// ---------------------------------------------------------------------------
static __device__ __forceinline__ void stage_tile(const float* __restrict__ x,
        int b0, int c0, int n4, int S, _Float16* __restrict__ d, int tid) {
    const int cnt = 32 * n4;
    for (int c = tid; c < cnt; c += 256) {
        int row = c / n4, ch = c - row * n4;
        float4 v = *(const float4*)(x + (size_t)(b0 + row) * DIMX + c0 + ch * 4);
        v4h p;
        p[0] = (_Float16)v.x; p[1] = (_Float16)v.y; p[2] = (_Float16)v.z; p[3] = (_Float16)v.w;
        *(v4h*)(&d[row * S + ch * 4]) = p;
    }
}

// f16-domain element extract (stays 16-bit; compiler uses op_sel halves)
#define XH(A, i) (A[(i) >> 3][(i) & 7])
// f32 extract (fallback kernel only)
#define XE(A, i) ((float)A[(i) >> 3][(i) & 7])

// Cross-wave kh-pair accumulator merge through LDS (reuses xs; max 24576 B).
// Hand-inlined macro with STATIC acc indices only: acc must never be
// address-taken (r1 post-mortem: pointer-escape demoted acc to scratch ->
// VGPR 48, WRITE_SIZE 545MB, no speedup). After this, kh==0 waves hold sums.
#define PAIR_REDUCE(NA)                                                  \
    {                                                                    \
        v4f* red_ = (v4f*)xs;                                            \
        __syncthreads();                                                 \
        if (kh) {                                                        \
            _Pragma("unroll")                                            \
            for (int a_ = 0; a_ < (NA); ++a_)                            \
                red_[(rt * 64 + lane) * (NA) + a_] = acc[a_];            \
        }                                                                \
        __syncthreads();                                                 \
        if (!kh) {                                                       \
            _Pragma("unroll")                                            \
            for (int a_ = 0; a_ < (NA); ++a_)                            \
                acc[a_] += red_[(rt * 64 + lane) * (NA) + a_];           \
        }                                                                \
    }

// ---------------------------------------------------------------------------
// Path-specialized kernel: 3072 blocks = 12 units x 256 batch-tiles of 32.
// fp16 pipeline (r4): af-fragments built with native f16 VALU; MFMA
// f32_16x16x32_f16. r6: __launch_bounds__(256,5) -> 5 blocks/CU (62.5%
// static occ; VGPR cap 102 >= 56 measured need). r5's (256,6) capped VGPR
// at ~85 and the unified arch+acc file spilled (VGPR 40, WRITE 508MB) —
// occupancy bound must clear the FULL arch+acc footprint, not just numRegs.
// Waves = (rt = row half, kh = K half); kh merged via PAIR_REDUCE.
//   out: p0a,p4,p9   pa: p1,p3,p7   pb: p2,p5,p8   pc: p0b,p6,p10
// ---------------------------------------------------------------------------
__global__ __launch_bounds__(256, 5) void tp_path(
    const float* __restrict__ x1, const float* __restrict__ x2,
    const _Float16* __restrict__ wt2, const float* __restrict__ cg,
    float* __restrict__ out, float* __restrict__ pa,
    float* __restrict__ pb, float* __restrict__ pc)
{
    __shared__ __align__(16) _Float16 xs[12800];
    const int tid  = threadIdx.x;
    const int lane = tid & 63;
    const int wv   = tid >> 6;
    const int quad = lane >> 4;
    const int l16  = lane & 15;
    const int rt   = wv & 1;
    const int kh   = wv >> 1;
    const int path = c_order[blockIdx.x >> 8];
    const int b0   = (blockIdx.x & 255) * 32;
    const int qil  = (quad * 16 + l16) * 8;
    const int lrow = rt * 16 + l16;

    const float c0n = sqrtf(1.0f / 21504.0f);
    const float c1n = sqrtf(3.0f / 20480.0f);
    const float c2n = sqrtf(5.0f / 13312.0f);

    switch (path) {
    case 0: case 11: { // (0,0,0) sec0, K 16384 split into halves of 8192
        float* __restrict__ dst = (path == 0) ? out : pc;
        const int ub = ((path == 11) ? 64 : 0) + kh * 32;
        const int S = 136;
        stage_tile(x1, b0, 0, 32, S, xs, tid);
        stage_tile(x2, b0, 0, 32, S, xs + 32*S, tid);
        __syncthreads();
        const _Float16* X1L = xs + lrow * S;
        const _Float16* X2L = xs + 32*S + lrow * S;
        const _Float16 s0h = (_Float16)(cg[0] * c0n);
        v4f acc[8];
        #pragma unroll
        for (int c = 0; c < 8; ++c) acc[c] = (v4f)0.f;
        #pragma unroll 1
        for (int u = ub; u < ub + 32; ++u) {
            const _Float16 sh = s0h * X1L[u];
            #pragma unroll 2
            for (int q4 = 0; q4 < 4; ++q4) {
                v8h xv = *(const v8h*)(X2L + 32*q4 + quad * 8);
                v8h af = xv * sh;                     // 4x v_pk_mul_f16
                const _Float16* bp = wt2 + (size_t)((u*4 + q4) * 8) * 512 + qil;
                #pragma unroll
                for (int ct = 0; ct < 8; ++ct) {
                    v8h bf = *(const v8h*)(bp + ct * 512);
                    acc[ct] = __builtin_amdgcn_mfma_f32_16x16x32_f16(af, bf, acc[ct], 0, 0, 0);
                }
            }
        }
        PAIR_REDUCE(8)
        if (!kh) {
            #pragma unroll
            for (int i = 0; i < 4; ++i) {
                int r = b0 + rt*16 + quad*4 + i;
                #pragma unroll
                for (int ct = 0; ct < 8; ++ct)
                    dst[(size_t)r * DIMX + ct*16 + l16] = acc[ct][i];
            }
        }
        break; }
    case 1: { // (1,1,0) sec0 -> pa, K 4096
        const int S = 200;
        stage_tile(x1, b0, 128, 48, S, xs, tid);
        stage_tile(x2, b0, 128, 48, S, xs + 32*S, tid);
        __syncthreads();
        const _Float16* X1L = xs + lrow * S;
        const _Float16* X2L = xs + 32*S + lrow * S;
        const float d0 = cg[44]*c0n, d1 = cg[48]*c0n, d2 = cg[52]*c0n;
        v4f acc[8];
        #pragma unroll
        for (int c = 0; c < 8; ++c) acc[c] = (v4f)0.f;
        #pragma unroll 1
        for (int tu = kh*32; tu < kh*32 + 32; ++tu) {
            const int u3 = 3 * tu;
            const _Float16 m0 = (_Float16)(d0*(float)X1L[u3]);
            const _Float16 m1 = (_Float16)(d1*(float)X1L[u3+1]);
            const _Float16 m2 = (_Float16)(d2*(float)X1L[u3+2]);
            #pragma unroll 1
            for (int h = 0; h < 2; ++h) {
                const int col = 96*h + 24*quad;
                v8h a[3];
                a[0] = *(const v8h*)(X2L + col);
                a[1] = *(const v8h*)(X2L + col + 8);
                a[2] = *(const v8h*)(X2L + col + 16);
                v8h af;
                #pragma unroll
                for (int j = 0; j < 8; ++j)
                    af[j] = m0*XH(a,3*j) + m1*XH(a,3*j+1) + m2*XH(a,3*j+2); // f16 fma chain
                const _Float16* bp = wt2 + (size_t)((512 + tu*2 + h) * 8) * 512 + qil;
                #pragma unroll
                for (int ct = 0; ct < 8; ++ct) {
                    v8h bf = *(const v8h*)(bp + ct * 512);
                    acc[ct] = __builtin_amdgcn_mfma_f32_16x16x32_f16(af, bf, acc[ct], 0, 0, 0);
                }
            }
        }
        PAIR_REDUCE(8)
        if (!kh) {
            #pragma unroll
            for (int i = 0; i < 4; ++i) {
                int r = b0 + rt*16 + quad*4 + i;
                #pragma unroll
                for (int ct = 0; ct < 8; ++ct)
                    pa[(size_t)r * DIMX + ct*16 + l16] = acc[ct][i];
            }
        }
        break; }
    case 2: { // (2,2,0) sec0 -> pb, K 1024
        const int S = 168;
        stage_tile(x1, b0, 320, 40, S, xs, tid);
        stage_tile(x2, b0, 320, 40, S, xs + 32*S, tid);
        __syncthreads();
        const _Float16* X1L = xs + lrow * S;
        const _Float16* X2L = xs + 32*S + lrow * S;
        v4f acc[8];
        #pragma unroll
        for (int c = 0; c < 8; ++c) acc[c] = (v4f)0.f;
        v8h a[5];   // x2 fragment is t-invariant: hoist out of the loop
        #pragma unroll
        for (int q = 0; q < 5; ++q) a[q] = *(const v8h*)(X2L + 40*quad + 8*q);
        #pragma unroll 1
        for (int t = kh*16; t < kh*16 + 16; ++t) {
            const int u5 = 5 * t;
            _Float16 m[5];
            #pragma unroll
            for (int kk = 0; kk < 5; ++kk)
                m[kk] = (_Float16)(cg[213+6*kk]*c0n*(float)X1L[u5+kk]);
            v8h af;
            #pragma unroll
            for (int j = 0; j < 8; ++j) {
                _Float16 s = (_Float16)0.f;
                #pragma unroll
                for (int kk = 0; kk < 5; ++kk) s += m[kk] * XH(a, 5*j+kk);
                af[j] = s;
            }
            const _Float16* bp = wt2 + (size_t)((640+t) * 8) * 512 + qil;
            #pragma unroll
            for (int ct = 0; ct < 8; ++ct) {
                v8h bf = *(const v8h*)(bp + ct * 512);
                acc[ct] = __builtin_amdgcn_mfma_f32_16x16x32_f16(af, bf, acc[ct], 0, 0, 0);
            }
        }
        PAIR_REDUCE(8)
        if (!kh) {
            #pragma unroll
            for (int i = 0; i < 4; ++i) {
                int r = b0 + rt*16 + quad*4 + i;
                #pragma unroll
                for (int ct = 0; ct < 8; ++ct)
                    pb[(size_t)r * DIMX + ct*16 + l16] = acc[ct][i];
            }
        }
        break; }
    case 3: { // (0,1,1) sec1 -> pa, K 8192
        const int S1 = 136, S2 = 200;
        stage_tile(x1, b0, 0,   32, S1, xs, tid);
        stage_tile(x2, b0, 128, 48, S2, xs + 32*S1, tid);
        __syncthreads();
        const _Float16* X1L = xs + lrow * S1;
        const _Float16* X2L = xs + 32*S1 + lrow * S2;
        const float g0 = cg[1]*c1n, g1 = cg[5]*c1n, g2 = cg[9]*c1n;
        v4f acc[12];   // [p*4 + cti]
        #pragma unroll
        for (int c = 0; c < 12; ++c) acc[c] = (v4f)0.f;
        #pragma unroll 1
        for (int tu = kh*64; tu < kh*64 + 64; ++tu) {
            const float xu = (float)X1L[tu];
            const _Float16 e0 = (_Float16)(g0*xu);
            const _Float16 e1 = (_Float16)(g1*xu);
            const _Float16 e2 = (_Float16)(g2*xu);
            #pragma unroll 1
            for (int h = 0; h < 2; ++h) {
                const int t = tu*2 + h;
                const int col = 96*h + 24*quad;
                v8h a[3];
                a[0] = *(const v8h*)(X2L + col);
                a[1] = *(const v8h*)(X2L + col + 8);
                a[2] = *(const v8h*)(X2L + col + 16);
                v8h af[3];
                #pragma unroll
                for (int j = 0; j < 8; ++j) {
                    af[0][j] = e0 * XH(a, 3*j);     // 1x v_mul_f16 each
                    af[1][j] = e1 * XH(a, 3*j+1);
                    af[2][j] = e2 * XH(a, 3*j+2);
                }
                const _Float16* bp = wt2 + 2752512 + (size_t)(t*4) * 512 + qil;
                #pragma unroll
                for (int cti = 0; cti < 4; ++cti) {
                    v8h bf = *(const v8h*)(bp + cti * 512);
                    #pragma unroll
                    for (int p = 0; p < 3; ++p)
                        acc[p*4+cti] = __builtin_amdgcn_mfma_f32_16x16x32_f16(af[p], bf, acc[p*4+cti], 0, 0, 0);
                }
            }
        }
        PAIR_REDUCE(12)
        if (!kh) {
            #pragma unroll
            for (int i = 0; i < 4; ++i) {
                int r = b0 + rt*16 + quad*4 + i;
                #pragma unroll
                for (int p = 0; p < 3; ++p)
                    #pragma unroll
                    for (int cti = 0; cti < 4; ++cti)
                        pa[(size_t)r * DIMX + 128 + (cti*16 + l16)*3 + p] = acc[p*4+cti][i];
            }
        }
        break; }
    case 4: { // (1,0,1) sec1 -> out, K 8192
        const int S1 = 200, S2 = 136;
        stage_tile(x1, b0, 128, 48, S1, xs, tid);
        stage_tile(x2, b0, 0,   32, S2, xs + 32*S1, tid);
        __syncthreads();
        const _Float16* X1L = xs + lrow * S1;
        const _Float16* X2L = xs + 32*S1 + lrow * S2;
        const float d0 = cg[35]*c1n, d1 = cg[39]*c1n, d2 = cg[43]*c1n;
        v4f acc[12];   // [p*4 + cti]
        #pragma unroll
        for (int c = 0; c < 12; ++c) acc[c] = (v4f)0.f;
        #pragma unroll 1
        for (int tu = kh*32; tu < kh*32 + 32; ++tu) {
            const int u3 = 3 * tu;
            const _Float16 m0 = (_Float16)(d0*(float)X1L[u3]);
            const _Float16 m1 = (_Float16)(d1*(float)X1L[u3+1]);
            const _Float16 m2 = (_Float16)(d2*(float)X1L[u3+2]);
            #pragma unroll 1
            for (int q4 = 0; q4 < 4; ++q4) {
                const int t = tu*4 + q4;
                v8h xv = *(const v8h*)(X2L + 32*q4 + quad*8);
                v8h af[3];
                af[0] = xv * m0;                      // vector pk_mul
                af[1] = xv * m1;
                af[2] = xv * m2;
                const _Float16* bp = wt2 + 2752512 + (size_t)((256+t)*4) * 512 + qil;
                #pragma unroll
                for (int cti = 0; cti < 4; ++cti) {
                    v8h bf = *(const v8h*)(bp + cti * 512);
                    #pragma unroll
                    for (int p = 0; p < 3; ++p)
                        acc[p*4+cti] = __builtin_amdgcn_mfma_f32_16x16x32_f16(af[p], bf, acc[p*4+cti], 0, 0, 0);
                }
            }
        }
        PAIR_REDUCE(12)
        if (!kh) {
            #pragma unroll
            for (int i = 0; i < 4; ++i) {
                int r = b0 + rt*16 + quad*4 + i;
                #pragma unroll
                for (int p = 0; p < 3; ++p)
                    #pragma unroll
                    for (int cti = 0; cti < 4; ++cti)
                        out[(size_t)r * DIMX + 128 + (cti*16 + l16)*3 + p] = acc[p*4+cti][i];
            }
        }
        break; }
    case 5: { // (1,2,1) sec1 -> pb, K 2048 (kept chh structure: reg pressure)
        const int chh = wv >> 1;
        const int S1 = 200, S2 = 168;
        stage_tile(x1, b0, 128, 48, S1, xs, tid);
        stage_tile(x2, b0, 320, 40, S2, xs + 32*S1, tid);
        __syncthreads();
        const _Float16* X1L = xs + lrow * S1;
        const _Float16* X2L = xs + 32*S1 + lrow * S2;
        v4f acc[3][2];
        for (int p = 0; p < 3; ++p) { acc[p][0] = (v4f)0.f; acc[p][1] = (v4f)0.f; }
        #pragma unroll 1
        for (int t = 0; t < 64; ++t) {
            const int u3 = 3 * t;
            float p1[3];
            #pragma unroll
            for (int i1 = 0; i1 < 3; ++i1) p1[i1] = c1n * (float)X1L[u3 + i1];
            _Float16 yh[5][3];
            #pragma unroll
            for (int j2 = 0; j2 < 5; ++j2)
                #pragma unroll
                for (int p = 0; p < 3; ++p)
                    yh[j2][p] = (_Float16)(cg[98 + (0*5+j2)*3 + p]*p1[0]
                                         + cg[98 + (1*5+j2)*3 + p]*p1[1]
                                         + cg[98 + (2*5+j2)*3 + p]*p1[2]);
            const int col = 40 * quad;
            v8h a[5];
            #pragma unroll
            for (int q = 0; q < 5; ++q) a[q] = *(const v8h*)(X2L + col + 8*q);
            v8h af[3];
            #pragma unroll
            for (int j = 0; j < 8; ++j) {
                _Float16 s0 = (_Float16)0.f, s1 = (_Float16)0.f, s2 = (_Float16)0.f;
                #pragma unroll
                for (int j2 = 0; j2 < 5; ++j2) {
                    _Float16 x = XH(a, 5*j + j2);
                    s0 += yh[j2][0]*x; s1 += yh[j2][1]*x; s2 += yh[j2][2]*x;
                }
                af[0][j] = s0; af[1][j] = s1; af[2][j] = s2;
            }
            #pragma unroll
            for (int cti = 0; cti < 2; ++cti) {
                v8h bf = *(const v8h*)(wt2 + 2752512 + (size_t)((512+t)*4 + chh*2 + cti)*512 + qil);
                #pragma unroll
                for (int p = 0; p < 3; ++p)
                    acc[p][cti] = __builtin_amdgcn_mfma_f32_16x16x32_f16(af[p], bf, acc[p][cti], 0, 0, 0);
            }
        }
        #pragma unroll
        for (int i = 0; i < 4; ++i) {
            int r = b0 + rt*16 + quad*4 + i;
            #pragma unroll
            for (int p = 0; p < 3; ++p)
                #pragma unroll
                for (int cti = 0; cti < 2; ++cti)
                    pb[(size_t)r * DIMX + 128 + ((chh*2+cti)*16 + l16)*3 + p] = acc[p][cti][i];
        }
        break; }
    case 6: { // (2,1,1) sec1 -> pc, K 2048
        const int S1 = 168, S2 = 200;
        stage_tile(x1, b0, 320, 40, S1, xs, tid);
        stage_tile(x2, b0, 128, 48, S2, xs + 32*S1, tid);
        __syncthreads();
        const _Float16* X1L = xs + lrow * S1;
        const _Float16* X2L = xs + 32*S1 + lrow * S2;
        v4f acc[12];   // [p*4 + cti]
        #pragma unroll
        for (int c = 0; c < 12; ++c) acc[c] = (v4f)0.f;
        #pragma unroll 1
        for (int tu = kh*16; tu < kh*16 + 16; ++tu) {
            const int u5 = 5 * tu;
            float p1[5];
            #pragma unroll
            for (int i1 = 0; i1 < 5; ++i1) p1[i1] = c1n * (float)X1L[u5 + i1];
            _Float16 yh[3][3];   // per-tu: halves the CG fma count
            #pragma unroll
            for (int j2 = 0; j2 < 3; ++j2)
                #pragma unroll
                for (int p = 0; p < 3; ++p) {
                    float s = 0.f;
                    #pragma unroll
                    for (int i1 = 0; i1 < 5; ++i1)
                        s += cg[168 + (i1*3+j2)*3 + p] * p1[i1];
                    yh[j2][p] = (_Float16)s;
                }
            #pragma unroll 1
            for (int h = 0; h < 2; ++h) {
                const int t = tu*2 + h;
                const int col = 96*h + 24*quad;
                v8h a[3];
                a[0] = *(const v8h*)(X2L + col);
                a[1] = *(const v8h*)(X2L + col + 8);
                a[2] = *(const v8h*)(X2L + col + 16);
                v8h af[3];
                #pragma unroll
                for (int j = 0; j < 8; ++j) {
                    _Float16 s0 = (_Float16)0.f, s1 = (_Float16)0.f, s2 = (_Float16)0.f;
                    #pragma unroll
                    for (int j2 = 0; j2 < 3; ++j2) {
                        _Float16 x = XH(a, 3*j + j2);
                        s0 += yh[j2][0]*x; s1 += yh[j2][1]*x; s2 += yh[j2][2]*x;
                    }
                    af[0][j] = s0; af[1][j] = s1; af[2][j] = s2;
                }
                const _Float16* bp = wt2 + 2752512 + (size_t)((576+t)*4) * 512 + qil;
                #pragma unroll
                for (int cti = 0; cti < 4; ++cti) {
                    v8h bf = *(const v8h*)(bp + cti * 512);
                    #pragma unroll
                    for (int p = 0; p < 3; ++p)
                        acc[p*4+cti] = __builtin_amdgcn_mfma_f32_16x16x32_f16(af[p], bf, acc[p*4+cti], 0, 0, 0);
                }
            }
        }
        PAIR_REDUCE(12)
        if (!kh) {
            #pragma unroll
            for (int i = 0; i < 4; ++i) {
                int r = b0 + rt*16 + quad*4 + i;
                #pragma unroll
                for (int p = 0; p < 3; ++p)
                    #pragma unroll
                    for (int cti = 0; cti < 4; ++cti)
                        pc[(size_t)r * DIMX + 128 + (cti*16 + l16)*3 + p] = acc[p*4+cti][i];
            }
        }
        break; }
    case 7: { // (0,2,2) sec2 -> pa, K 4096
        const int S1 = 136, S2 = 168;
        stage_tile(x1, b0, 0,   32, S1, xs, tid);
        stage_tile(x2, b0, 320, 40, S2, xs + 32*S1, tid);
        __syncthreads();
        const _Float16* X1L = xs + lrow * S1;
        const _Float16* X2L = xs + 32*S1 + lrow * S2;
        v4f acc[10];   // [kk*2 + cti]
        #pragma unroll
        for (int c = 0; c < 10; ++c) acc[c] = (v4f)0.f;
        v8h a[5];   // t-invariant x2 fragment: hoist
        #pragma unroll
        for (int q = 0; q < 5; ++q) a[q] = *(const v8h*)(X2L + 40*quad + 8*q);
        #pragma unroll 1
        for (int t = kh*64; t < kh*64 + 64; ++t) {
            const float xu = c2n * (float)X1L[t];
            _Float16 e[5];
            #pragma unroll
            for (int kk = 0; kk < 5; ++kk) e[kk] = (_Float16)(cg[10 + 6*kk] * xu);
            v8h af[5];
            #pragma unroll
            for (int j = 0; j < 8; ++j)
                #pragma unroll
                for (int kk = 0; kk < 5; ++kk)
                    af[kk][j] = e[kk] * XH(a, 5*j + kk);   // 1x v_mul_f16 each
            const _Float16* bp = wt2 + 4063232 + (size_t)(t*2) * 512 + qil;
            #pragma unroll
            for (int cti = 0; cti < 2; ++cti) {
                v8h bf = *(const v8h*)(bp + cti * 512);
                #pragma unroll
                for (int kk = 0; kk < 5; ++kk)
                    acc[kk*2+cti] = __builtin_amdgcn_mfma_f32_16x16x32_f16(af[kk], bf, acc[kk*2+cti], 0, 0, 0);
            }
        }
        PAIR_REDUCE(10)
        if (!kh) {
            #pragma unroll
            for (int i = 0; i < 4; ++i) {
                int r = b0 + rt*16 + quad*4 + i;
                #pragma unroll
                for (int kk = 0; kk < 5; ++kk)
                    #pragma unroll
                    for (int cti = 0; cti < 2; ++cti)
                        pa[(size_t)r * DIMX + 320 + (cti*16 + l16)*5 + kk] = acc[kk*2+cti][i];
            }
        }
        break; }
    case 8: { // (1,1,2) sec2 -> pb, K 4096
        const int S = 200;
        stage_tile(x1, b0, 128, 48, S, xs, tid);
        stage_tile(x2, b0, 128, 48, S, xs + 32*S, tid);
        __syncthreads();
        const _Float16* X1L = xs + lrow * S;
        const _Float16* X2L = xs + 32*S + lrow * S;
        v4f acc[10];   // [kk*2 + cti]
        #pragma unroll
        for (int c = 0; c < 10; ++c) acc[c] = (v4f)0.f;
        #pragma unroll 1
        for (int tu = kh*32; tu < kh*32 + 32; ++tu) {
            const int u3 = 3 * tu;
            float p1[3];
            #pragma unroll
            for (int i1 = 0; i1 < 3; ++i1) p1[i1] = c2n * (float)X1L[u3 + i1];
            _Float16 yh[3][5];   // per-tu
            #pragma unroll
            for (int j2 = 0; j2 < 3; ++j2)
                #pragma unroll
                for (int kk = 0; kk < 5; ++kk)
                    yh[j2][kk] = (_Float16)(cg[53 + (0*3+j2)*5 + kk]*p1[0]
                                          + cg[53 + (1*3+j2)*5 + kk]*p1[1]
                                          + cg[53 + (2*3+j2)*5 + kk]*p1[2]);
            #pragma unroll 1
            for (int h = 0; h < 2; ++h) {
                const int t = tu*2 + h;
                const int col = 96*h + 24*quad;
                v8h a[3];
                a[0] = *(const v8h*)(X2L + col);
                a[1] = *(const v8h*)(X2L + col + 8);
                a[2] = *(const v8h*)(X2L + col + 16);
                v8h af[5];
                #pragma unroll
                for (int j = 0; j < 8; ++j) {
                    _Float16 s[5] = {(_Float16)0.f, (_Float16)0.f, (_Float16)0.f,
                                     (_Float16)0.f, (_Float16)0.f};
                    #pragma unroll
                    for (int j2 = 0; j2 < 3; ++j2) {
                        _Float16 x = XH(a, 3*j + j2);
                        #pragma unroll
                        for (int kk = 0; kk < 5; ++kk) s[kk] += yh[j2][kk] * x;
                    }
                    #pragma unroll
                    for (int kk = 0; kk < 5; ++kk) af[kk][j] = s[kk];
                }
                const _Float16* bp = wt2 + 4063232 + (size_t)((128+t)*2) * 512 + qil;
                #pragma unroll
                for (int cti = 0; cti < 2; ++cti) {
                    v8h bf = *(const v8h*)(bp + cti * 512);
                    #pragma unroll
                    for (int kk = 0; kk < 5; ++kk)
                        acc[kk*2+cti] = __builtin_amdgcn_mfma_f32_16x16x32_f16(af[kk], bf, acc[kk*2+cti], 0, 0, 0);
                }
            }
        }
        PAIR_REDUCE(10)
        if (!kh) {
            #pragma unroll
            for (int i = 0; i < 4; ++i) {
                int r = b0 + rt*16 + quad*4 + i;
                #pragma unroll
                for (int kk = 0; kk < 5; ++kk)
                    #pragma unroll
                    for (int cti = 0; cti < 2; ++cti)
                        pb[(size_t)r * DIMX + 320 + (cti*16 + l16)*5 + kk] = acc[kk*2+cti][i];
            }
        }
        break; }
    case 9: { // (2,0,2) sec2 -> out, K 4096
        const int S1 = 168, S2 = 136;
        stage_tile(x1, b0, 320, 40, S1, xs, tid);
        stage_tile(x2, b0, 0,   32, S2, xs + 32*S1, tid);
        __syncthreads();
        const _Float16* X1L = xs + lrow * S1;
        const _Float16* X2L = xs + 32*S1 + lrow * S2;
        v4f acc[10];   // [kk*2 + cti]
        #pragma unroll
        for (int c = 0; c < 10; ++c) acc[c] = (v4f)0.f;
        #pragma unroll 1
        for (int tu = kh*16; tu < kh*16 + 16; ++tu) {
            const int u5 = 5 * tu;
            _Float16 m[5];
            #pragma unroll
            for (int kk = 0; kk < 5; ++kk)
                m[kk] = (_Float16)(cg[143 + 6*kk] * c2n * (float)X1L[u5 + kk]);
            #pragma unroll 1
            for (int q4 = 0; q4 < 4; ++q4) {
                const int t = tu*4 + q4;
                v8h xv = *(const v8h*)(X2L + 32*q4 + quad*8);
                v8h af[5];
                #pragma unroll
                for (int kk = 0; kk < 5; ++kk) af[kk] = xv * m[kk];  // vector pk_mul
                const _Float16* bp = wt2 + 4063232 + (size_t)((256+t)*2) * 512 + qil;
                #pragma unroll
                for (int cti = 0; cti < 2; ++cti) {
                    v8h bf = *(const v8h*)(bp + cti * 512);
                    #pragma unroll
                    for (int kk = 0; kk < 5; ++kk)
                        acc[kk*2+cti] = __builtin_amdgcn_mfma_f32_16x16x32_f16(af[kk], bf, acc[kk*2+cti], 0, 0, 0);
                }
            }
        }
        PAIR_REDUCE(10)
        if (!kh) {
            #pragma unroll
            for (int i = 0; i < 4; ++i) {
                int r = b0 + rt*16 + quad*4 + i;
                #pragma unroll
                for (int kk = 0; kk < 5; ++kk)
                    #pragma unroll
                    for (int cti = 0; cti < 2; ++cti)
                        out[(size_t)r * DIMX + 320 + (cti*16 + l16)*5 + kk] = acc[kk*2+cti][i];
            }
        }
        break; }
    default: { // case 10: (2,2,2) sec2 -> pc, K 1024 (kept chh structure)
        const int chh = wv >> 1;
        const int S = 168;
        stage_tile(x1, b0, 320, 40, S, xs, tid);
        stage_tile(x2, b0, 320, 40, S, xs + 32*S, tid);
        __syncthreads();
        const _Float16* X1L = xs + lrow * S;
        const _Float16* X2L = xs + 32*S + lrow * S;
        v4f acc[5]; for (int p = 0; p < 5; ++p) acc[p] = (v4f)0.f;
        #pragma unroll 1
        for (int t = 0; t < 32; ++t) {
            const int u5 = 5 * t;
            float p1[5];
            #pragma unroll
            for (int i1 = 0; i1 < 5; ++i1) p1[i1] = c2n * (float)X1L[u5 + i1];
            _Float16 yh[5][5];
            #pragma unroll
            for (int j2 = 0; j2 < 5; ++j2)
                #pragma unroll
                for (int kk = 0; kk < 5; ++kk) {
                    float s = 0.f;
                    #pragma unroll
                    for (int i1 = 0; i1 < 5; ++i1)
                        s += cg[238 + (i1*5+j2)*5 + kk] * p1[i1];
                    yh[j2][kk] = (_Float16)s;
                }
            const int col = 40 * quad;
            v8h a[5];
            #pragma unroll
            for (int q = 0; q < 5; ++q) a[q] = *(const v8h*)(X2L + col + 8*q);
            v8h af[5];
            #pragma unroll
            for (int j = 0; j < 8; ++j) {
                _Float16 s[5] = {(_Float16)0.f, (_Float16)0.f, (_Float16)0.f,
                                 (_Float16)0.f, (_Float16)0.f};
                #pragma unroll
                for (int j2 = 0; j2 < 5; ++j2) {
                    _Float16 x = XH(a, 5*j + j2);
                    #pragma unroll
                    for (int kk = 0; kk < 5; ++kk) s[kk] += yh[j2][kk] * x;
                }
                #pragma unroll
                for (int kk = 0; kk < 5; ++kk) af[kk][j] = s[kk];
            }
            v8h bf = *(const v8h*)(wt2 + 4063232 + (size_t)((384+t)*2 + chh)*512 + qil);
            #pragma unroll
            for (int kk = 0; kk < 5; ++kk)
                acc[kk] = __builtin_amdgcn_mfma_f32_16x16x32_f16(af[kk], bf, acc[kk], 0, 0, 0);
        }
        #pragma unroll
        for (int i = 0; i < 4; ++i) {
            int r = b0 + rt*16 + quad*4 + i;
            #pragma unroll
            for (int kk = 0; kk < 5; ++kk)
                pc[(size_t)r * DIMX + 320 + (chh*16 + l16)*5 + kk] = acc[kk][i];
        }
        break; }
    }
}

// out += pa + pb + pc (all buffers fully populated, column-disjoint per path).
// 983040 float4, 3840 blocks.
__global__ void add3_kernel(float4* __restrict__ o, const float4* __restrict__ pa,
                            const float4* __restrict__ pb, const float4* __restrict__ pc) {
    size_t i = (size_t)blockIdx.x * 256 + threadIdx.x;
    float4 r = o[i], a = pa[i], b = pb[i], c = pc[i];
    r.x += a.x + b.x + c.x; r.y += a.y + b.y + c.y;
    r.z += a.z + b.z + c.z; r.w += a.w + b.w + c.w;
    o[i] = r;
}

// ---------------------------------------------------------------------------
// Fallback (round-6 kernel, verified; fp16 port): used when ws is small.
// ---------------------------------------------------------------------------
template<bool UW>
__global__ __launch_bounds__(256, 2) void tp_fb(
    const float* __restrict__ x1, const float* __restrict__ x2,
    const float* __restrict__ w, const _Float16* __restrict__ wt2,
    const float* __restrict__ cg, float* __restrict__ out)
{
    __shared__ _Float16 x1s[32 * 488];
    __shared__ _Float16 x2s[32 * 488];
    const int tid  = threadIdx.x;
    const int lane = tid & 63;
    const int wv   = tid >> 6;
    const int quad = lane >> 4;
    const int l16  = lane & 15;
    const int sec  = blockIdx.x % 3;
    const int bt   = blockIdx.x / 3;
    const int b0   = bt * 32;

    for (int c = tid; c < 3840; c += 256) {
        int row = c / 120, ch = c - row * 120;
        float4 v1 = *(const float4*)(x1 + (size_t)(b0 + row) * DIMX + ch * 4);
        float4 v2 = *(const float4*)(x2 + (size_t)(b0 + row) * DIMX + ch * 4);
        v4h p1, p2;
        p1[0]=(_Float16)v1.x; p1[1]=(_Float16)v1.y; p1[2]=(_Float16)v1.z; p1[3]=(_Float16)v1.w;
        p2[0]=(_Float16)v2.x; p2[1]=(_Float16)v2.y; p2[2]=(_Float16)v2.z; p2[3]=(_Float16)v2.w;
        *(v4h*)(&x1s[row * 488 + ch * 4]) = p1;
        *(v4h*)(&x2s[row * 488 + ch * 4]) = p2;
    }
    __syncthreads();

    const int rt  = wv & 1;
    const int chh = wv >> 1;
    const int lrow = rt * 16 + l16;
    const _Float16* X1L = x1s + lrow * 488;
    const _Float16* X2L = x2s + lrow * 488;

    if (sec == 0) {
        const float c0 = sqrtf(1.0f / 21504.0f);
        v4f acc[4];
        #pragma unroll
        for (int b = 0; b < 4; ++b) acc[b] = (v4f)0.f;
        const _Float16* wtw = wt2 + (size_t)(quad * 16 + l16) * 8;
        #pragma unroll 1
        for (int t = 0; t < 336; ++t) {
            const int kt = t * 64;
            v8h af[2];
            if (kt < 16384) {
                const int u = kt >> 7;
                const float s = cg[0] * c0 * (float)X1L[u];
                #pragma unroll
                for (int ks = 0; ks < 2; ++ks) {
                    v8h xv = *(const v8h*)(X2L + (kt & 127) + ks * 32 + quad * 8);
                    #pragma unroll
                    for (int j = 0; j < 8; ++j) af[ks][j] = (_Float16)(s * (float)xv[j]);
                }
            } else if (kt < 20480) {
                const int u = (kt - 16384) >> 6;
                const float m0 = cg[44]*c0*(float)X1L[128+3*u];
                const float m1 = cg[48]*c0*(float)X1L[128+3*u+1];
                const float m2 = cg[52]*c0*(float)X1L[128+3*u+2];
                #pragma unroll
                for (int ks = 0; ks < 2; ++ks) {
                    const int col = 128 + 3 * (ks * 32 + quad * 8);
                    v8h xv[3];
                    xv[0] = *(const v8h*)(X2L + col);
                    xv[1] = *(const v8h*)(X2L + col + 8);
                    xv[2] = *(const v8h*)(X2L + col + 16);
                    #pragma unroll
                    for (int j = 0; j < 8; ++j)
                        af[ks][j] = (_Float16)(m0*XE(xv,3*j) + m1*XE(xv,3*j+1) + m2*XE(xv,3*j+2));
                }
            } else {
                #pragma unroll
                for (int ks = 0; ks < 2; ++ks) {
                    const int u = ((kt - 20480) >> 5) + ks;
                    float m[5];
                    #pragma unroll
                    for (int k = 0; k < 5; ++k)
                        m[k] = cg[213 + 6*k] * c0 * (float)X1L[320 + 5*u + k];
                    const int col = 320 + 40 * quad;
                    v8h xv[5];
                    #pragma unroll
                    for (int q = 0; q < 5; ++q) xv[q] = *(const v8h*)(X2L + col + 8*q);
                    #pragma unroll
                    for (int j = 0; j < 8; ++j) {
                        float a = 0.f;
                        #pragma unroll
                        for (int k = 0; k < 5; ++k) a += m[k] * XE(xv, 5*j+k);
                        af[ks][j] = (_Float16)a;
                    }
                }
            }
            #pragma unroll
            for (int ks = 0; ks < 2; ++ks) {
                const int kblk = (kt >> 5) + ks;
                #pragma unroll
                for (int ct = 0; ct < 4; ++ct) {
                    v8h bf;
                    if (UW) {
                        bf = *(const v8h*)(wtw + (size_t)(kblk * 8 + chh * 4 + ct) * 512);
                    } else {
                        int rb, pb;
                        if (kt < 16384)      { rb = 0;     pb = 0; }
                        else if (kt < 20480) { rb = 16384; pb = 3276800; }
                        else                 { rb = 20480; pb = 4325376; }
                        const float* src = w + pb + (size_t)(kt + ks*32 + quad*8 - rb) * 128
                                           + (chh*4 + ct)*16 + l16;
                        #pragma unroll
                        for (int j = 0; j < 8; ++j) bf[j] = (_Float16)src[(size_t)j * 128];
                    }
                    acc[ct] = __builtin_amdgcn_mfma_f32_16x16x32_f16(af[ks], bf, acc[ct], 0, 0, 0);
                }
            }
        }
        #pragma unroll
        for (int i = 0; i < 4; ++i) {
            const int r = b0 + rt*16 + quad*4 + i;
            float* orow = out + (size_t)r * DIMX;
            #pragma unroll
            for (int ct = 0; ct < 4; ++ct) orow[chh*64 + ct*16 + l16] = acc[ct][i];
        }
    } else if (sec == 1) {
        const float c1 = sqrtf(3.0f / 20480.0f);
        v4f acc[3][2];
        #pragma unroll
        for (int p = 0; p < 3; ++p) { acc[p][0] = (v4f)0.f; acc[p][1] = (v4f)0.f; }
        const _Float16* wtw = wt2 + 2752512 + (size_t)(quad * 16 + l16) * 8;
        #pragma unroll 1
        for (int t = 0; t < 640; ++t) {
            const int kt = t * 32;
            v8h af[3];
            if (kt < 8192) {
                const int u = kt >> 6;
                const float xv1 = (float)X1L[u];
                const float e0 = cg[1]*c1*xv1, e1 = cg[5]*c1*xv1, e2 = cg[9]*c1*xv1;
                const int col = 128 + 3 * ((kt & 63) + quad * 8);
                v8h xv[3];
                xv[0] = *(const v8h*)(X2L + col);
                xv[1] = *(const v8h*)(X2L + col + 8);
                xv[2] = *(const v8h*)(X2L + col + 16);
                #pragma unroll
                for (int j = 0; j < 8; ++j) {
                    af[0][j] = (_Float16)(e0 * XE(xv, 3*j));
                    af[1][j] = (_Float16)(e1 * XE(xv, 3*j+1));
                    af[2][j] = (_Float16)(e2 * XE(xv, 3*j+2));
                }
            } else if (kt < 16384) {
                const int q0 = kt - 8192;
                const int u = q0 >> 7;
                const float m0 = cg[35]*c1*(float)X1L[128+3*u];
                const float m1 = cg[39]*c1*(float)X1L[128+3*u+1];
                const float m2 = cg[43]*c1*(float)X1L[128+3*u+2];
                v8h xv = *(const v8h*)(X2L + (q0 & 127) + quad * 8);
                #pragma unroll
                for (int j = 0; j < 8; ++j) {
                    float x = (float)xv[j];
                    af[0][j] = (_Float16)(m0 * x);
                    af[1][j] = (_Float16)(m1 * x);
                    af[2][j] = (_Float16)(m2 * x);
                }
            } else if (kt < 18432) {
                const int u = (kt - 16384) >> 5;
                float p1[3];
                #pragma unroll
                for (int i1 = 0; i1 < 3; ++i1) p1[i1] = c1 * (float)X1L[128 + 3*u + i1];
                float y[5][3];
                #pragma unroll
                for (int j2 = 0; j2 < 5; ++j2)
                    #pragma unroll
                    for (int k = 0; k < 3; ++k)
                        y[j2][k] = cg[98 + (0*5+j2)*3 + k]*p1[0]
                                 + cg[98 + (1*5+j2)*3 + k]*p1[1]
                                 + cg[98 + (2*5+j2)*3 + k]*p1[2];
                const int col = 320 + 40 * quad;
                v8h xv[5];
                #pragma unroll
                for (int q = 0; q < 5; ++q) xv[q] = *(const v8h*)(X2L + col + 8*q);
                #pragma unroll
                for (int j = 0; j < 8; ++j) {
                    float a0 = 0.f, a1 = 0.f, a2 = 0.f;
                    #pragma unroll
                    for (int j2 = 0; j2 < 5; ++j2) {
                        float x = XE(xv, 5*j + j2);
                        a0 += y[j2][0]*x; a1 += y[j2][1]*x; a2 += y[j2][2]*x;
                    }
                    af[0][j] = (_Float16)a0; af[1][j] = (_Float16)a1; af[2][j] = (_Float16)a2;
                }
            } else {
                const int q0 = kt - 18432;
                const int u = q0 >> 6;
                float p1[5];
                #pragma unroll
                for (int i1 = 0; i1 < 5; ++i1) p1[i1] = c1 * (float)X1L[320 + 5*u + i1];
                float y[3][3];
                #pragma unroll
                for (int j2 = 0; j2 < 3; ++j2)
                    #pragma unroll
                    for (int k = 0; k < 3; ++k) {
                        float s = 0.f;
                        #pragma unroll
                        for (int i1 = 0; i1 < 5; ++i1)
                            s += cg[168 + (i1*3+j2)*3 + k] * p1[i1];
                        y[j2][k] = s;
                    }
                const int col = 128 + 3 * ((q0 & 63) + quad * 8);
                v8h xv[3];
                xv[0] = *(const v8h*)(X2L + col);
                xv[1] = *(const v8h*)(X2L + col + 8);
                xv[2] = *(const v8h*)(X2L + col + 16);
                #pragma unroll
                for (int j = 0; j < 8; ++j) {
                    float a0 = 0.f, a1 = 0.f, a2 = 0.f;
                    #pragma unroll
                    for (int j2 = 0; j2 < 3; ++j2) {
                        float x = XE(xv, 3*j + j2);
                        a0 += y[j2][0]*x; a1 += y[j2][1]*x; a2 += y[j2][2]*x;
                    }
                    af[0][j] = (_Float16)a0; af[1][j] = (_Float16)a1; af[2][j] = (_Float16)a2;
                }
            }
            #pragma unroll
            for (int cti = 0; cti < 2; ++cti) {
                const int nblk = chh * 2 + cti;
                v8h bf;
                if (UW) {
                    bf = *(const v8h*)(wtw + (size_t)(t * 4 + nblk) * 512);
                } else {
                    int rb, pb;
                    if (kt < 8192)       { rb = 0;     pb = 2097152; }
                    else if (kt < 16384) { rb = 8192;  pb = 2752512; }
                    else if (kt < 18432) { rb = 16384; pb = 3932160; }
                    else                 { rb = 18432; pb = 4194304; }
                    const float* src = w + pb + (size_t)(kt + quad*8 - rb) * 64 + nblk*16 + l16;
                    #pragma unroll
                    for (int j = 0; j < 8; ++j) bf[j] = (_Float16)src[(size_t)j * 64];
                }
                #pragma unroll
                for (int p = 0; p < 3; ++p)
                    acc[p][cti] = __builtin_amdgcn_mfma_f32_16x16x32_f16(af[p], bf, acc[p][cti], 0, 0, 0);
            }
        }
        #pragma unroll
        for (int i = 0; i < 4; ++i) {
            const int r = b0 + rt*16 + quad*4 + i;
            float* orow = out + (size_t)r * DIMX;
            #pragma unroll
            for (int p = 0; p < 3; ++p)
                #pragma unroll
                for (int cti = 0; cti < 2; ++cti)
                    orow[128 + ((chh*2 + cti)*16 + l16) * 3 + p] = acc[p][cti][i];
        }
    } else {
        const float c2 = sqrtf(5.0f / 13312.0f);
        v4f acc[5];
        #pragma unroll
        for (int p = 0; p < 5; ++p) acc[p] = (v4f)0.f;
        const _Float16* wtw = wt2 + 4063232 + (size_t)(quad * 16 + l16) * 8;
        #pragma unroll 1
        for (int t = 0; t < 416; ++t) {
            const int kt = t * 32;
            v8h af[5];
            if (kt < 4096) {
                const int u = kt >> 5;
                const float s = c2 * (float)X1L[u];
                float e[5];
                #pragma unroll
                for (int k = 0; k < 5; ++k) e[k] = cg[10 + 6*k] * s;
                const int col = 320 + 40 * quad;
                v8h xv[5];
                #pragma unroll
                for (int q = 0; q < 5; ++q) xv[q] = *(const v8h*)(X2L + col + 8*q);
                #pragma unroll
                for (int j = 0; j < 8; ++j)
                    #pragma unroll
                    for (int k = 0; k < 5; ++k)
                        af[k][j] = (_Float16)(e[k] * XE(xv, 5*j + k));
            } else if (kt < 8192) {
                const int q0 = kt - 4096;
                const int u = q0 >> 6;
                float p1[3];
                #pragma unroll
                for (int i1 = 0; i1 < 3; ++i1) p1[i1] = c2 * (float)X1L[128 + 3*u + i1];
                float y[3][5];
                #pragma unroll
                for (int j2 = 0; j2 < 3; ++j2)
                    #pragma unroll
                    for (int k = 0; k < 5; ++k)
                        y[j2][k] = cg[53 + (0*3+j2)*5 + k]*p1[0]
                                 + cg[53 + (1*3+j2)*5 + k]*p1[1]
                                 + cg[53 + (2*3+j2)*5 + k]*p1[2];
                const int col = 128 + 3 * ((q0 & 63) + quad * 8);
                v8h xv[3];
                xv[0] = *(const v8h*)(X2L + col);
                xv[1] = *(const v8h*)(X2L + col + 8);
                xv[2] = *(const v8h*)(X2L + col + 16);
                #pragma unroll
                for (int j = 0; j < 8; ++j) {
                    float a[5] = {0.f, 0.f, 0.f, 0.f, 0.f};
                    #pragma unroll
                    for (int j2 = 0; j2 < 3; ++j2) {
                        float x = XE(xv, 3*j + j2);
                        #pragma unroll
                        for (int k = 0; k < 5; ++k) a[k] += y[j2][k] * x;
                    }
                    #pragma unroll
                    for (int k = 0; k < 5; ++k) af[k][j] = (_Float16)a[k];
                }
            } else if (kt < 12288) {
                const int q0 = kt - 8192;
                const int u = q0 >> 7;
                float m[5];
                #pragma unroll
                for (int k = 0; k < 5; ++k)
                    m[k] = cg[143 + 6*k] * c2 * (float)X1L[320 + 5*u + k];
                v8h xv = *(const v8h*)(X2L + (q0 & 127) + quad * 8);
                #pragma unroll
                for (int j = 0; j < 8; ++j) {
                    float x = (float)xv[j];
                    #pragma unroll
                    for (int k = 0; k < 5; ++k) af[k][j] = (_Float16)(m[k] * x);
                }
            } else {
                const int u = (kt - 12288) >> 5;
                float p1[5];
                #pragma unroll
                for (int i1 = 0; i1 < 5; ++i1) p1[i1] = c2 * (float)X1L[320 + 5*u + i1];
                float y[5][5];
                #pragma unroll
                for (int j2 = 0; j2 < 5; ++j2)
                    #pragma unroll
                    for (int k = 0; k < 5; ++k) {
                        float s = 0.f;
                        #pragma unroll
                        for (int i1 = 0; i1 < 5; ++i1)
                            s += cg[238 + (i1*5+j2)*5 + k] * p1[i1];
                        y[j2][k] = s;
                    }
                const int col = 320 + 40 * quad;
                v8h xv[5];
                #pragma unroll
                for (int q = 0; q < 5; ++q) xv[q] = *(const v8h*)(X2L + col + 8*q);
                #pragma unroll
                for (int j = 0; j < 8; ++j) {
                    float a[5] = {0.f, 0.f, 0.f, 0.f, 0.f};
                    #pragma unroll
                    for (int j2 = 0; j2 < 5; ++j2) {
                        float x = XE(xv, 5*j + j2);
                        #pragma unroll
                        for (int k = 0; k < 5; ++k) a[k] += y[j2][k] * x;
                    }
                    #pragma unroll
                    for (int k = 0; k < 5; ++k) af[k][j] = (_Float16)a[k];
                }
            }
            {
                v8h bf;
                if (UW) {
                    bf = *(const v8h*)(wtw + (size_t)(t * 2 + chh) * 512);
                } else {
                    int rb, pb;
                    if (kt < 4096)       { rb = 0;     pb = 2621440; }
                    else if (kt < 8192)  { rb = 4096;  pb = 3801088; }
                    else if (kt < 12288) { rb = 8192;  pb = 4063232; }
                    else                 { rb = 12288; pb = 4456448; }
                    const float* src = w + pb + (size_t)(kt + quad*8 - rb) * 32 + chh*16 + l16;
                    #pragma unroll
                    for (int j = 0; j < 8; ++j) bf[j] = (_Float16)src[(size_t)j * 32];
                }
                #pragma unroll
                for (int k = 0; k < 5; ++k)
                    acc[k] = __builtin_amdgcn_mfma_f32_16x16x32_f16(af[k], bf, acc[k], 0, 0, 0);
            }
        }
        #pragma unroll
        for (int i = 0; i < 4; ++i) {
            const int r = b0 + rt*16 + quad*4 + i;
            float* orow = out + (size_t)r * DIMX;
            #pragma unroll
            for (int k = 0; k < 5; ++k)
                orow[320 + (chh*16 + l16) * 5 + k] = acc[k][i];
        }
    }
}

extern "C" void kernel_launch(void* const* d_in, const int* in_sizes, int n_in,
                              void* d_out, int out_size, void* d_ws, size_t ws_size,
                              hipStream_t stream) {
    const float* x1 = (const float*)d_in[0];
    const float* x2 = (const float*)d_in[1];
    const float* wt_f = (const float*)d_in[2];
    float* out = (float*)d_out;
    (void)in_sizes; (void)n_in; (void)out_size;

    static float h_cg[363];
    static bool h_cg_done = false;
    if (!h_cg_done) { build_cg_host(h_cg); h_cg_done = true; }

    const size_t WT_BYTES = (size_t)4489216 * 2;                 // 8,978,432
    const size_t CG_PAD   = 4096;
    const size_t PART     = (size_t)8192 * DIMX * 4;             // 15,728,640
    const size_t PA_OFF   = WT_BYTES + CG_PAD;
    const size_t NEED     = PA_OFF + 3 * PART;                   // 56,168,448

    float*    cgp = (float*)((char*)d_ws + WT_BYTES);
    _Float16* wtp = (_Float16*)d_ws;
    float*    pa  = (float*)((char*)d_ws + PA_OFF);
    float*    pb  = (float*)((char*)d_ws + PA_OFF + PART);
    float*    pc  = (float*)((char*)d_ws + PA_OFF + 2 * PART);

    if (ws_size >= NEED) {
        hipMemcpyAsync(cgp, h_cg, sizeof(h_cg), hipMemcpyHostToDevice, stream);
        wt2_kernel<<<dim3(2192), dim3(256), 0, stream>>>(wt_f, wtp);
        tp_path<<<dim3(3072), dim3(256), 0, stream>>>(x1, x2, wtp, cgp, out, pa, pb, pc);
        add3_kernel<<<dim3(3840), dim3(256), 0, stream>>>(
            (float4*)out, (const float4*)pa, (const float4*)pb, (const float4*)pc);
    } else if (ws_size >= WT_BYTES + CG_PAD) {
        hipMemcpyAsync(cgp, h_cg, sizeof(h_cg), hipMemcpyHostToDevice, stream);
        wt2_kernel<<<dim3(2192), dim3(256), 0, stream>>>(wt_f, wtp);
        tp_fb<true><<<dim3(768), dim3(256), 0, stream>>>(x1, x2, wt_f, wtp, cgp, out);
    } else {
        float* cgs = (float*)d_ws;
        hipMemcpyAsync(cgs, h_cg, sizeof(h_cg), hipMemcpyHostToDevice, stream);
        tp_fb<false><<<dim3(768), dim3(256), 0, stream>>>(x1, x2, wt_f, (const _Float16*)d_ws, cgs, out);
    }
}